// Round 1
// baseline (356.924 us; speedup 1.0000x reference)
//
// DANet dual-attention block, MI355X/gfx950.
// R1 design:
//  - everything matmul-shaped runs as bf16 NT-GEMM (m97 128x128 2-barrier
//    structure, mfma_f32_16x16x32_bf16, global_load_lds width-16 staging)
//  - PA softmax: |E|<~6 => p=exp(E) unnormalized (exact softmax up to the
//    row-constant), 1/rowsum folded into PV epilogue
//  - CA softmax: literal (rowmax - E) two-max form (diag ~ 4096)
//  - out = gamma_pa*PA + 2x  (PV epilogue), then += gamma_ca*CA (CA epilogue)
//  - P [G][4096][4096] bf16 materialized in d_ws, G chosen from ws_size
#include <hip/hip_runtime.h>

#define CH   512
#define NPIX 4096
#define CQ   32
#define MR   640   // 512 (wv) + 32 (wq) + 32 (wk) + 64 zero pad
#define NB   4

typedef unsigned short u16;
typedef __bf16 bf16x8 __attribute__((ext_vector_type(8)));
typedef float  f32x4  __attribute__((ext_vector_type(4)));
typedef unsigned int uint4v __attribute__((ext_vector_type(4)));

__device__ __forceinline__ u16 f2bf(float f) {
  union { float f; unsigned int u; } v; v.f = f;
  unsigned int r = v.u + 0x7FFFu + ((v.u >> 16) & 1u);   // RNE
  return (u16)(r >> 16);
}

__device__ __forceinline__ void gload_lds16(const u16* g, u16* l) {
  __builtin_amdgcn_global_load_lds(
      (const __attribute__((address_space(1))) unsigned int*)g,
      (__attribute__((address_space(3))) unsigned int*)l, 16, 0, 0);
}

// ---------------- weight stack: Wb[640][512] bf16, biasS[640] ----------------
__global__ void k_prep_w(const float* __restrict__ wq, const float* __restrict__ bq,
                         const float* __restrict__ wk, const float* __restrict__ bk,
                         const float* __restrict__ wv, const float* __restrict__ bv,
                         u16* __restrict__ Wb, float* __restrict__ biasS) {
  int idx = blockIdx.x * 256 + threadIdx.x;
  if (idx < MR * CH) {
    int r = idx >> 9, c = idx & 511;
    float v = 0.f;
    if (r < 512)      v = wv[r * CH + c];
    else if (r < 544) v = wq[(r - 512) * CH + c];
    else if (r < 576) v = wk[(r - 544) * CH + c];
    Wb[idx] = f2bf(v);
  }
  if (idx < MR) {
    float v = 0.f;
    if (idx < 512)      v = bv[idx];
    else if (idx < 544) v = bq[idx - 512];
    else if (idx < 576) v = bk[idx - 544];
    biasS[idx] = v;
  }
}

// ------------- x -> Xb bf16 [B][512][4096], Xt bf16 [B][4096][512] -----------
__global__ __launch_bounds__(256) void k_convert(const float* __restrict__ x,
                                                 u16* __restrict__ Xb,
                                                 u16* __restrict__ Xt) {
  __shared__ float tile[64][65];                     // +1 pad: conflict-free transpose
  const int b = blockIdx.z, ct = blockIdx.y, nt = blockIdx.x;
  const int t = threadIdx.x, tn = t & 63, tg = t >> 6;
  const size_t xbase = ((size_t)b * CH + ct * 64) * NPIX + nt * 64;
#pragma unroll
  for (int i = 0; i < 16; ++i) {
    int cl = tg * 16 + i;
    float v = x[xbase + (size_t)cl * NPIX + tn];
    Xb[xbase + (size_t)cl * NPIX + tn] = f2bf(v);
    tile[cl][tn] = v;
  }
  __syncthreads();
  const size_t tbase = ((size_t)b * NPIX + nt * 64) * CH + ct * 64;
#pragma unroll
  for (int i = 0; i < 16; ++i) {
    int nl = tg * 16 + i;
    Xt[tbase + (size_t)nl * CH + tn] = f2bf(tile[tn][nl]);
  }
}

// --------------------------- generic NT bf16 GEMM ----------------------------
// C[i][j] = sum_k A[i][k]*B[j][k]; A:[M][K], B:[N][K] row-major bf16.
// 128x128 tile, 4 waves (2x2 quadrants of 64x64), BK=32, 2 barriers/K-step.
enum { EP_QKV = 0, EP_PLAIN = 1, EP_PV = 2, EP_CA = 3 };

template <int EP>
__global__ __launch_bounds__(256) void gemm_nt(
    const u16* __restrict__ Aall, const u16* __restrict__ Ball,
    long sA, long sB, int K, int zBase,
    void* pa0, void* pa1, void* pa2, const float* pg) {
  __shared__ u16 Alds[128 * 32];
  __shared__ u16 Blds[128 * 32];
  const int t = threadIdx.x, l = t & 63, w = t >> 6;
  const int wr = w >> 1, wc = w & 1;
  const int z = blockIdx.z;
  const u16* A = Aall + (size_t)z * sA;
  const u16* B = Ball + (size_t)z * sB;
  const int rowBase = blockIdx.x * 128, colBase = blockIdx.y * 128;

  f32x4 acc[4][4];
#pragma unroll
  for (int i = 0; i < 4; ++i)
#pragma unroll
    for (int j = 0; j < 4; ++j) acc[i][j] = f32x4{0.f, 0.f, 0.f, 0.f};

  const int rs0 = l >> 2, cs0 = (l & 3) * 8;

  for (int k0 = 0; k0 < K; k0 += 32) {
    __syncthreads();                       // prev iter's LDS reads done
#pragma unroll
    for (int i = 0; i < 2; ++i) {          // stage A,B tiles (8KB each, linear)
      int chunk = w * 2 + i;
      int r = chunk * 16 + rs0;
      gload_lds16(A + (size_t)(rowBase + r) * K + k0 + cs0, Alds + chunk * 512);
      gload_lds16(B + (size_t)(colBase + r) * K + k0 + cs0, Blds + chunk * 512);
    }
    __syncthreads();                       // vmcnt(0) drained by barrier
    bf16x8 af[4], bfr[4];
#pragma unroll
    for (int i = 0; i < 4; ++i) {
      af[i]  = *(const bf16x8*)(Alds + (wr * 64 + i * 16 + (l & 15)) * 32 + (l >> 4) * 8);
      bfr[i] = *(const bf16x8*)(Blds + (wc * 64 + i * 16 + (l & 15)) * 32 + (l >> 4) * 8);
    }
#pragma unroll
    for (int i = 0; i < 4; ++i)
#pragma unroll
      for (int j = 0; j < 4; ++j)
        acc[i][j] = __builtin_amdgcn_mfma_f32_16x16x32_bf16(af[i], bfr[j], acc[i][j], 0, 0, 0);
  }

  // D layout: col = lane&15, row = (lane>>4)*4 + reg   [m89/m91 verified]
  const int b = zBase + z;
  if constexpr (EP == EP_QKV) {
    u16* Vb = (u16*)pa0; u16* Qt = (u16*)pa1; u16* Kt = (u16*)pa2;
#pragma unroll
    for (int i = 0; i < 4; ++i)
#pragma unroll
      for (int r = 0; r < 4; ++r) {
        int row = rowBase + wr * 64 + i * 16 + (l >> 4) * 4 + r;
        if (row >= 576) continue;
        float bias = pg[row];
#pragma unroll
        for (int j = 0; j < 4; ++j) {
          int col = colBase + wc * 64 + j * 16 + (l & 15);
          u16 h = f2bf(acc[i][j][r] + bias);
          if (row < 512)      Vb[((size_t)b * CH + row) * NPIX + col] = h;
          else if (row < 544) Qt[((size_t)b * NPIX + col) * CQ + (row - 512)] = h;
          else                Kt[((size_t)b * NPIX + col) * CQ + (row - 544)] = h;
        }
      }
  } else if constexpr (EP == EP_PLAIN) {   // CA energy, fp32 [b][512][512]
    float* C = (float*)pa0;
#pragma unroll
    for (int i = 0; i < 4; ++i)
#pragma unroll
      for (int j = 0; j < 4; ++j)
#pragma unroll
        for (int r = 0; r < 4; ++r) {
          int row = rowBase + wr * 64 + i * 16 + (l >> 4) * 4 + r;
          int col = colBase + wc * 64 + j * 16 + (l & 15);
          C[((size_t)b * CH + row) * CH + col] = acc[i][j][r];
        }
  } else if constexpr (EP == EP_PV) {      // out = gpa*acc/rowsum + 2x
    float* out = (float*)pa0; const float* xg = (const float*)pa1;
    const float* rsum = (const float*)pa2;
    const float gv = pg[0];
#pragma unroll
    for (int j = 0; j < 4; ++j) {
      int col = colBase + wc * 64 + j * 16 + (l & 15);
      float rinv = 1.0f / rsum[(size_t)b * NPIX + col];
#pragma unroll
      for (int i = 0; i < 4; ++i)
#pragma unroll
        for (int r = 0; r < 4; ++r) {
          int row = rowBase + wr * 64 + i * 16 + (l >> 4) * 4 + r;
          size_t idx = ((size_t)b * CH + row) * NPIX + col;
          out[idx] = gv * acc[i][j][r] * rinv + 2.0f * xg[idx];
        }
    }
  } else {                                  // EP_CA: out += gca*acc
    float* out = (float*)pa0;
    const float gv = pg[0];
#pragma unroll
    for (int i = 0; i < 4; ++i)
#pragma unroll
      for (int j = 0; j < 4; ++j)
#pragma unroll
        for (int r = 0; r < 4; ++r) {
          int row = rowBase + wr * 64 + i * 16 + (l >> 4) * 4 + r;
          int col = colBase + wc * 64 + j * 16 + (l & 15);
          size_t idx = ((size_t)b * CH + row) * NPIX + col;
          out[idx] += gv * acc[i][j][r];
        }
  }
}

// ------ PA energy: P[z][n][m] = exp(Qt[n]·Kt[m]) bf16 (unnorm), rowsums ------
// block: 64 query rows (4 waves x 16), m staged in 256-key chunks.
__global__ __launch_bounds__(256) void k_energy(
    const u16* __restrict__ Qt, const u16* __restrict__ Kt,
    u16* __restrict__ P, float* __restrict__ rsum, int zBase) {
  __shared__ u16 Klds[256 * 32];       // 16 KB
  __shared__ u16 pbuf[4][16 * 256];    // 32 KB, per-wave staging for coalesced P writes
  const int t = threadIdx.x, l = t & 63, w = t >> 6;
  const int z = blockIdx.z, b = zBase + z;
  const int qbase = blockIdx.x * 64;
  const u16* Qtb = Qt + (size_t)b * NPIX * CQ;
  const u16* Ktb = Kt + (size_t)b * NPIX * CQ;
  u16* Pz = P + (size_t)z * NPIX * NPIX;

  const int arow = qbase + w * 16 + (l & 15);
  const bf16x8 af = *(const bf16x8*)(Qtb + (size_t)arow * CQ + (l >> 4) * 8);
  const f32x4 zero = {0.f, 0.f, 0.f, 0.f};

  float rs[4] = {0.f, 0.f, 0.f, 0.f};
  const int rs0 = l >> 2, cs0 = (l & 3) * 8;
  u16* pw = pbuf[w];

  for (int mc = 0; mc < NPIX; mc += 256) {
    __syncthreads();
#pragma unroll
    for (int i = 0; i < 4; ++i) {
      int chunk = w * 4 + i;
      int r = chunk * 16 + rs0;
      gload_lds16(Ktb + (size_t)(mc + r) * CQ + cs0, Klds + chunk * 512);
    }
    __syncthreads();
#pragma unroll
    for (int mb = 0; mb < 16; ++mb) {
      bf16x8 bfr = *(const bf16x8*)(Klds + (mb * 16 + (l & 15)) * 32 + (l >> 4) * 8);
      f32x4 e = __builtin_amdgcn_mfma_f32_16x16x32_bf16(af, bfr, zero, 0, 0, 0);
#pragma unroll
      for (int r = 0; r < 4; ++r) {
        float p = __expf(e[r]);
        rs[r] += p;
        pw[((l >> 4) * 4 + r) * 256 + mb * 16 + (l & 15)] = f2bf(p);
      }
    }
    asm volatile("s_waitcnt lgkmcnt(0)" ::: "memory");   // pbuf writes visible wave-wide
#pragma unroll
    for (int it = 0; it < 8; ++it) {                     // coalesced 512B-row P writes
      int offb = it * 1024 + l * 16;
      int rowI = offb >> 9;
      int colH = (offb & 511) >> 1;
      uint4v v = *(const uint4v*)((const char*)pw + offb);
      *(uint4v*)(Pz + (size_t)(qbase + w * 16 + rowI) * NPIX + mc + colH) = v;
    }
  }
#pragma unroll
  for (int o = 1; o < 16; o <<= 1)
#pragma unroll
    for (int r = 0; r < 4; ++r) rs[r] += __shfl_xor(rs[r], o);
  if ((l & 15) == 0) {
#pragma unroll
    for (int r = 0; r < 4; ++r)
      rsum[(size_t)b * NPIX + qbase + w * 16 + (l >> 4) * 4 + r] = rs[r];
  }
}

// --------- CA softmax: Aca[row][d] = softmax_d(rowmax - E) in bf16 -----------
__global__ __launch_bounds__(256) void k_ca_softmax(const float* __restrict__ CAE,
                                                    u16* __restrict__ Aca) {
  const int l = threadIdx.x & 63, w = threadIdx.x >> 6;
  const int row = blockIdx.x * 4 + w;   // [0, NB*512)
  const float* e = CAE + (size_t)row * CH;
  f32x4 a = *(const f32x4*)(e + l * 8);
  f32x4 c = *(const f32x4*)(e + l * 8 + 4);
  float m1 = fmaxf(fmaxf(fmaxf(a[0], a[1]), fmaxf(a[2], a[3])),
                   fmaxf(fmaxf(c[0], c[1]), fmaxf(c[2], c[3])));
  for (int o = 1; o < 64; o <<= 1) m1 = fmaxf(m1, __shfl_xor(m1, o));
  float en[8];
#pragma unroll
  for (int i = 0; i < 4; ++i) { en[i] = m1 - a[i]; en[4 + i] = m1 - c[i]; }
  float m2 = en[0];
#pragma unroll
  for (int i = 1; i < 8; ++i) m2 = fmaxf(m2, en[i]);
  for (int o = 1; o < 64; o <<= 1) m2 = fmaxf(m2, __shfl_xor(m2, o));
  float p[8], s = 0.f;
#pragma unroll
  for (int i = 0; i < 8; ++i) { p[i] = __expf(en[i] - m2); s += p[i]; }
  for (int o = 1; o < 64; o <<= 1) s += __shfl_xor(s, o);
  const float inv = 1.0f / s;
  union { u16 h[8]; uint4v v; } u;
#pragma unroll
  for (int i = 0; i < 8; ++i) u.h[i] = f2bf(p[i] * inv);
  *(uint4v*)(Aca + (size_t)row * CH + l * 8) = u.v;
}

// --------------------------------- host --------------------------------------
extern "C" void kernel_launch(void* const* d_in, const int* in_sizes, int n_in,
                              void* d_out, int out_size, void* d_ws, size_t ws_size,
                              hipStream_t stream) {
  const float* x   = (const float*)d_in[0];
  const float* wq  = (const float*)d_in[1];
  const float* bq  = (const float*)d_in[2];
  const float* wk  = (const float*)d_in[3];
  const float* bk  = (const float*)d_in[4];
  const float* wv  = (const float*)d_in[5];
  const float* bv  = (const float*)d_in[6];
  const float* gpa = (const float*)d_in[7];
  const float* gca = (const float*)d_in[8];
  float* out = (float*)d_out;

  char* wsp = (char*)d_ws;
  size_t off = 0;
  auto alloc = [&](size_t bytes) -> void* {
    void* p = (void*)(wsp + off);
    off = (off + bytes + 255) & ~(size_t)255;
    return p;
  };
  const size_t EB = (size_t)NB * CH * NPIX;            // elems in a [B][512][4096]
  u16*   Xb    = (u16*)alloc(EB * 2);
  u16*   Xt    = (u16*)alloc(EB * 2);
  u16*   Wb    = (u16*)alloc((size_t)MR * CH * 2);
  float* biasS = (float*)alloc((size_t)MR * 4);
  u16*   Vb    = (u16*)alloc(EB * 2);
  u16*   Qt    = (u16*)alloc((size_t)NB * NPIX * CQ * 2);
  u16*   Kt    = (u16*)alloc((size_t)NB * NPIX * CQ * 2);
  float* rsum  = (float*)alloc((size_t)NB * NPIX * 4);
  float* CAE   = (float*)alloc((size_t)NB * CH * CH * 4);
  u16*   Aca   = (u16*)alloc((size_t)NB * CH * CH * 2);
  const size_t PSZ = (size_t)NPIX * NPIX * 2;          // one batch of P, bytes
  int G = (ws_size > off) ? (int)((ws_size - off) / PSZ) : 1;
  if (G > NB) G = NB;
  if (G < 1) G = 1;
  u16* P = (u16*)alloc((size_t)G * PSZ);

  k_prep_w<<<(MR * CH + 255) / 256, 256, 0, stream>>>(wq, bq, wk, bk, wv, bv, Wb, biasS);
  k_convert<<<dim3(64, 8, NB), 256, 0, stream>>>(x, Xb, Xt);

  // QKV: [640][512] x [4096][512]^T  -> Vb, Qt, Kt (+bias)
  gemm_nt<EP_QKV><<<dim3(MR / 128, NPIX / 128, NB), 256, 0, stream>>>(
      Wb, Xt, 0L, (long)NPIX * CH, CH, 0, Vb, Qt, Kt, biasS);

  // CA energy: Xb x Xb^T (K=4096) -> CAE fp32
  gemm_nt<EP_PLAIN><<<dim3(CH / 128, CH / 128, NB), 256, 0, stream>>>(
      Xb, Xb, (long)CH * NPIX, (long)CH * NPIX, NPIX, 0, CAE, nullptr, nullptr, nullptr);
  k_ca_softmax<<<NB * CH / 4, 256, 0, stream>>>(CAE, Aca);

  // PA, grouped by available scratch
  for (int b0 = 0; b0 < NB; b0 += G) {
    int gc = (NB - b0 < G) ? (NB - b0) : G;
    k_energy<<<dim3(NPIX / 64, 1, gc), 256, 0, stream>>>(Qt, Kt, P, rsum, b0);
    gemm_nt<EP_PV><<<dim3(CH / 128, NPIX / 128, gc), 256, 0, stream>>>(
        Vb + (size_t)b0 * CH * NPIX, P, (long)CH * NPIX, (long)NPIX * NPIX,
        NPIX, b0, out, (void*)x, rsum, gpa);
  }

  // CA out: Aca x Xt^T (K=512), accumulate gca into out
  gemm_nt<EP_CA><<<dim3(CH / 128, NPIX / 128, NB), 256, 0, stream>>>(
      Aca, Xt, (long)CH * CH, (long)NPIX * CH, CH, 0, out, nullptr, nullptr, gca);
}

// Round 2
// 287.129 us; speedup vs baseline: 1.2431x; 1.2431x over previous
//
// DANet dual-attention block, MI355X/gfx950.
// R2: + XCD-chunked bijective grid swizzle (T1/m204) on all GEMMs + energy
//     + CA-energy split-K x4 (64 -> 256 blocks), reduce folded into softmax
#include <hip/hip_runtime.h>

#define CH   512
#define NPIX 4096
#define CQ   32
#define MR   640   // 512 (wv) + 32 (wq) + 32 (wk) + 64 zero pad
#define NB   4

typedef unsigned short u16;
typedef __bf16 bf16x8 __attribute__((ext_vector_type(8)));
typedef float  f32x4  __attribute__((ext_vector_type(4)));
typedef unsigned int uint4v __attribute__((ext_vector_type(4)));

__device__ __forceinline__ u16 f2bf(float f) {
  union { float f; unsigned int u; } v; v.f = f;
  unsigned int r = v.u + 0x7FFFu + ((v.u >> 16) & 1u);   // RNE
  return (u16)(r >> 16);
}

__device__ __forceinline__ void gload_lds16(const u16* g, u16* l) {
  __builtin_amdgcn_global_load_lds(
      (const __attribute__((address_space(1))) unsigned int*)g,
      (__attribute__((address_space(3))) unsigned int*)l, 16, 0, 0);
}

// XCD-chunked bijective swizzle (nwg % 8 == 0 required; else identity).
__device__ __forceinline__ int xcd_swz(int flat, int nwg) {
  if (nwg & 7) return flat;
  return (flat & 7) * (nwg >> 3) + (flat >> 3);
}

// ---------------- weight stack: Wb[640][512] bf16, biasS[640] ----------------
__global__ void k_prep_w(const float* __restrict__ wq, const float* __restrict__ bq,
                         const float* __restrict__ wk, const float* __restrict__ bk,
                         const float* __restrict__ wv, const float* __restrict__ bv,
                         u16* __restrict__ Wb, float* __restrict__ biasS) {
  int idx = blockIdx.x * 256 + threadIdx.x;
  if (idx < MR * CH) {
    int r = idx >> 9, c = idx & 511;
    float v = 0.f;
    if (r < 512)      v = wv[r * CH + c];
    else if (r < 544) v = wq[(r - 512) * CH + c];
    else if (r < 576) v = wk[(r - 544) * CH + c];
    Wb[idx] = f2bf(v);
  }
  if (idx < MR) {
    float v = 0.f;
    if (idx < 512)      v = bv[idx];
    else if (idx < 544) v = bq[idx - 512];
    else if (idx < 576) v = bk[idx - 544];
    biasS[idx] = v;
  }
}

// ------------- x -> Xb bf16 [B][512][4096], Xt bf16 [B][4096][512] -----------
__global__ __launch_bounds__(256) void k_convert(const float* __restrict__ x,
                                                 u16* __restrict__ Xb,
                                                 u16* __restrict__ Xt) {
  __shared__ float tile[64][65];
  const int b = blockIdx.z, ct = blockIdx.y, nt = blockIdx.x;
  const int t = threadIdx.x, tn = t & 63, tg = t >> 6;
  const size_t xbase = ((size_t)b * CH + ct * 64) * NPIX + nt * 64;
#pragma unroll
  for (int i = 0; i < 16; ++i) {
    int cl = tg * 16 + i;
    float v = x[xbase + (size_t)cl * NPIX + tn];
    Xb[xbase + (size_t)cl * NPIX + tn] = f2bf(v);
    tile[cl][tn] = v;
  }
  __syncthreads();
  const size_t tbase = ((size_t)b * NPIX + nt * 64) * CH + ct * 64;
#pragma unroll
  for (int i = 0; i < 16; ++i) {
    int nl = tg * 16 + i;
    Xt[tbase + (size_t)nl * CH + tn] = f2bf(tile[tn][nl]);
  }
}

// --------------------------- generic NT bf16 GEMM ----------------------------
// C[i][j] = sum_k A[i][k]*B[j][k]; A,B row-major bf16 with row stride ld.
// 128x128 tile, 4 waves (2x2 quadrants of 64x64), BK=32, 2 barriers/K-step.
enum { EP_QKV = 0, EP_PART = 1, EP_PV = 2, EP_CA = 3 };

template <int EP>
__global__ __launch_bounds__(256) void gemm_nt(
    const u16* __restrict__ Aall, const u16* __restrict__ Ball,
    long sA, long sB, int K, int ld, int zBase,
    void* pa0, void* pa1, void* pa2, const float* pg) {
  __shared__ u16 Alds[128 * 32];
  __shared__ u16 Blds[128 * 32];
  const int nbx = gridDim.x, nby = gridDim.y;
  const int nwg = nbx * nby * gridDim.z;
  int flat = blockIdx.x + nbx * (blockIdx.y + nby * blockIdx.z);
  flat = xcd_swz(flat, nwg);
  const int bx = flat % nbx, by = (flat / nbx) % nby, bz = flat / (nbx * nby);

  const int t = threadIdx.x, l = t & 63, w = t >> 6;
  const int wr = w >> 1, wc = w & 1;
  size_t aoff, boff;
  if constexpr (EP == EP_PART) {           // bz = b*4 + kslice
    aoff = (size_t)(bz >> 2) * sA + (size_t)(bz & 3) * 1024;
    boff = (size_t)(bz >> 2) * sB + (size_t)(bz & 3) * 1024;
  } else {
    aoff = (size_t)bz * sA;
    boff = (size_t)bz * sB;
  }
  const u16* A = Aall + aoff;
  const u16* B = Ball + boff;
  const int rowBase = bx * 128, colBase = by * 128;

  f32x4 acc[4][4];
#pragma unroll
  for (int i = 0; i < 4; ++i)
#pragma unroll
    for (int j = 0; j < 4; ++j) acc[i][j] = f32x4{0.f, 0.f, 0.f, 0.f};

  const int rs0 = l >> 2, cs0 = (l & 3) * 8;

  for (int k0 = 0; k0 < K; k0 += 32) {
    __syncthreads();
#pragma unroll
    for (int i = 0; i < 2; ++i) {
      int chunk = w * 2 + i;
      int r = chunk * 16 + rs0;
      gload_lds16(A + (size_t)(rowBase + r) * ld + k0 + cs0, Alds + chunk * 512);
      gload_lds16(B + (size_t)(colBase + r) * ld + k0 + cs0, Blds + chunk * 512);
    }
    __syncthreads();
    bf16x8 af[4], bfr[4];
#pragma unroll
    for (int i = 0; i < 4; ++i) {
      af[i]  = *(const bf16x8*)(Alds + (wr * 64 + i * 16 + (l & 15)) * 32 + (l >> 4) * 8);
      bfr[i] = *(const bf16x8*)(Blds + (wc * 64 + i * 16 + (l & 15)) * 32 + (l >> 4) * 8);
    }
#pragma unroll
    for (int i = 0; i < 4; ++i)
#pragma unroll
      for (int j = 0; j < 4; ++j)
        acc[i][j] = __builtin_amdgcn_mfma_f32_16x16x32_bf16(af[i], bfr[j], acc[i][j], 0, 0, 0);
  }

  // D layout: col = lane&15, row = (lane>>4)*4 + reg   [m89/m91 verified]
  const int b = zBase + bz;
  if constexpr (EP == EP_QKV) {
    u16* Vb = (u16*)pa0; u16* Qt = (u16*)pa1; u16* Kt = (u16*)pa2;
#pragma unroll
    for (int i = 0; i < 4; ++i)
#pragma unroll
      for (int r = 0; r < 4; ++r) {
        int row = rowBase + wr * 64 + i * 16 + (l >> 4) * 4 + r;
        if (row >= 576) continue;
        float bias = pg[row];
#pragma unroll
        for (int j = 0; j < 4; ++j) {
          int col = colBase + wc * 64 + j * 16 + (l & 15);
          u16 h = f2bf(acc[i][j][r] + bias);
          if (row < 512)      Vb[((size_t)b * CH + row) * NPIX + col] = h;
          else if (row < 544) Qt[((size_t)b * NPIX + col) * CQ + (row - 512)] = h;
          else                Kt[((size_t)b * NPIX + col) * CQ + (row - 544)] = h;
        }
      }
  } else if constexpr (EP == EP_PART) {    // CA energy partial, fp32 [bz][512][512]
    float* C = (float*)pa0;
#pragma unroll
    for (int i = 0; i < 4; ++i)
#pragma unroll
      for (int j = 0; j < 4; ++j)
#pragma unroll
        for (int r = 0; r < 4; ++r) {
          int row = rowBase + wr * 64 + i * 16 + (l >> 4) * 4 + r;
          int col = colBase + wc * 64 + j * 16 + (l & 15);
          C[((size_t)bz * CH + row) * CH + col] = acc[i][j][r];
        }
  } else if constexpr (EP == EP_PV) {      // out = gpa*acc/rowsum + 2x
    float* out = (float*)pa0; const float* xg = (const float*)pa1;
    const float* rsum = (const float*)pa2;
    const float gv = pg[0];
#pragma unroll
    for (int j = 0; j < 4; ++j) {
      int col = colBase + wc * 64 + j * 16 + (l & 15);
      float rinv = 1.0f / rsum[(size_t)b * NPIX + col];
#pragma unroll
      for (int i = 0; i < 4; ++i)
#pragma unroll
        for (int r = 0; r < 4; ++r) {
          int row = rowBase + wr * 64 + i * 16 + (l >> 4) * 4 + r;
          size_t idx = ((size_t)b * CH + row) * NPIX + col;
          out[idx] = gv * acc[i][j][r] * rinv + 2.0f * xg[idx];
        }
    }
  } else {                                  // EP_CA: out += gca*acc
    float* out = (float*)pa0;
    const float gv = pg[0];
#pragma unroll
    for (int i = 0; i < 4; ++i)
#pragma unroll
      for (int j = 0; j < 4; ++j)
#pragma unroll
        for (int r = 0; r < 4; ++r) {
          int row = rowBase + wr * 64 + i * 16 + (l >> 4) * 4 + r;
          int col = colBase + wc * 64 + j * 16 + (l & 15);
          size_t idx = ((size_t)b * CH + row) * NPIX + col;
          out[idx] += gv * acc[i][j][r];
        }
  }
}

// ------ PA energy: P[z][n][m] = exp(Qt[n]·Kt[m]) bf16 (unnorm), rowsums ------
__global__ __launch_bounds__(256) void k_energy(
    const u16* __restrict__ Qt, const u16* __restrict__ Kt,
    u16* __restrict__ P, float* __restrict__ rsum, int zBase) {
  __shared__ u16 Klds[256 * 32];
  __shared__ u16 pbuf[4][16 * 256];
  const int nwg = gridDim.x * gridDim.z;
  int flat = blockIdx.x + gridDim.x * blockIdx.z;
  flat = xcd_swz(flat, nwg);
  const int qtile = flat % gridDim.x, z = flat / gridDim.x;

  const int t = threadIdx.x, l = t & 63, w = t >> 6;
  const int b = zBase + z;
  const int qbase = qtile * 64;
  const u16* Qtb = Qt + (size_t)b * NPIX * CQ;
  const u16* Ktb = Kt + (size_t)b * NPIX * CQ;
  u16* Pz = P + (size_t)z * NPIX * NPIX;

  const int arow = qbase + w * 16 + (l & 15);
  const bf16x8 af = *(const bf16x8*)(Qtb + (size_t)arow * CQ + (l >> 4) * 8);
  const f32x4 zero = {0.f, 0.f, 0.f, 0.f};

  float rs[4] = {0.f, 0.f, 0.f, 0.f};
  const int rs0 = l >> 2, cs0 = (l & 3) * 8;
  u16* pw = pbuf[w];

  for (int mc = 0; mc < NPIX; mc += 256) {
    __syncthreads();
#pragma unroll
    for (int i = 0; i < 4; ++i) {
      int chunk = w * 4 + i;
      int r = chunk * 16 + rs0;
      gload_lds16(Ktb + (size_t)(mc + r) * CQ + cs0, Klds + chunk * 512);
    }
    __syncthreads();
#pragma unroll
    for (int mb = 0; mb < 16; ++mb) {
      bf16x8 bfr = *(const bf16x8*)(Klds + (mb * 16 + (l & 15)) * 32 + (l >> 4) * 8);
      f32x4 e = __builtin_amdgcn_mfma_f32_16x16x32_bf16(af, bfr, zero, 0, 0, 0);
#pragma unroll
      for (int r = 0; r < 4; ++r) {
        float p = __expf(e[r]);
        rs[r] += p;
        pw[((l >> 4) * 4 + r) * 256 + mb * 16 + (l & 15)] = f2bf(p);
      }
    }
    asm volatile("s_waitcnt lgkmcnt(0)" ::: "memory");
#pragma unroll
    for (int it = 0; it < 8; ++it) {
      int offb = it * 1024 + l * 16;
      int rowI = offb >> 9;
      int colH = (offb & 511) >> 1;
      uint4v v = *(const uint4v*)((const char*)pw + offb);
      *(uint4v*)(Pz + (size_t)(qbase + w * 16 + rowI) * NPIX + mc + colH) = v;
    }
  }
#pragma unroll
  for (int o = 1; o < 16; o <<= 1)
#pragma unroll
    for (int r = 0; r < 4; ++r) rs[r] += __shfl_xor(rs[r], o);
  if ((l & 15) == 0) {
#pragma unroll
    for (int r = 0; r < 4; ++r)
      rsum[(size_t)b * NPIX + qbase + w * 16 + (l >> 4) * 4 + r] = rs[r];
  }
}

// --- CA softmax: sum 4 split-K partials, Aca[row][d]=softmax_d(rowmax-E) -----
__global__ __launch_bounds__(256) void k_ca_softmax(const float* __restrict__ CAEp,
                                                    u16* __restrict__ Aca) {
  const int l = threadIdx.x & 63, w = threadIdx.x >> 6;
  const int row = blockIdx.x * 4 + w;   // [0, NB*512)
  const int b = row >> 9, r = row & 511;
  float en0[8];
#pragma unroll
  for (int i = 0; i < 8; ++i) en0[i] = 0.f;
#pragma unroll
  for (int ks = 0; ks < 4; ++ks) {
    const float* e = CAEp + (((size_t)(b * 4 + ks) * CH + r) * CH);
    f32x4 a = *(const f32x4*)(e + l * 8);
    f32x4 c = *(const f32x4*)(e + l * 8 + 4);
#pragma unroll
    for (int i = 0; i < 4; ++i) { en0[i] += a[i]; en0[4 + i] += c[i]; }
  }
  float m1 = en0[0];
#pragma unroll
  for (int i = 1; i < 8; ++i) m1 = fmaxf(m1, en0[i]);
  for (int o = 1; o < 64; o <<= 1) m1 = fmaxf(m1, __shfl_xor(m1, o));
  float en[8];
#pragma unroll
  for (int i = 0; i < 8; ++i) en[i] = m1 - en0[i];
  float m2 = en[0];
#pragma unroll
  for (int i = 1; i < 8; ++i) m2 = fmaxf(m2, en[i]);
  for (int o = 1; o < 64; o <<= 1) m2 = fmaxf(m2, __shfl_xor(m2, o));
  float p[8], s = 0.f;
#pragma unroll
  for (int i = 0; i < 8; ++i) { p[i] = __expf(en[i] - m2); s += p[i]; }
  for (int o = 1; o < 64; o <<= 1) s += __shfl_xor(s, o);
  const float inv = 1.0f / s;
  union { u16 h[8]; uint4v v; } u;
#pragma unroll
  for (int i = 0; i < 8; ++i) u.h[i] = f2bf(p[i] * inv);
  *(uint4v*)(Aca + (size_t)row * CH + l * 8) = u.v;
}

// --------------------------------- host --------------------------------------
extern "C" void kernel_launch(void* const* d_in, const int* in_sizes, int n_in,
                              void* d_out, int out_size, void* d_ws, size_t ws_size,
                              hipStream_t stream) {
  const float* x   = (const float*)d_in[0];
  const float* wq  = (const float*)d_in[1];
  const float* bq  = (const float*)d_in[2];
  const float* wk  = (const float*)d_in[3];
  const float* bk  = (const float*)d_in[4];
  const float* wv  = (const float*)d_in[5];
  const float* bv  = (const float*)d_in[6];
  const float* gpa = (const float*)d_in[7];
  const float* gca = (const float*)d_in[8];
  float* out = (float*)d_out;

  char* wsp = (char*)d_ws;
  size_t off = 0;
  auto alloc = [&](size_t bytes) -> void* {
    void* p = (void*)(wsp + off);
    off = (off + bytes + 255) & ~(size_t)255;
    return p;
  };
  const size_t EB = (size_t)NB * CH * NPIX;
  u16*   Xb    = (u16*)alloc(EB * 2);
  u16*   Xt    = (u16*)alloc(EB * 2);
  u16*   Wb    = (u16*)alloc((size_t)MR * CH * 2);
  float* biasS = (float*)alloc((size_t)MR * 4);
  u16*   Vb    = (u16*)alloc(EB * 2);
  u16*   Qt    = (u16*)alloc((size_t)NB * NPIX * CQ * 2);
  u16*   Kt    = (u16*)alloc((size_t)NB * NPIX * CQ * 2);
  float* rsum  = (float*)alloc((size_t)NB * NPIX * 4);
  float* CAEp  = (float*)alloc((size_t)NB * 4 * CH * CH * 4);   // split-K partials
  u16*   Aca   = (u16*)alloc((size_t)NB * CH * CH * 2);
  const size_t PSZ = (size_t)NPIX * NPIX * 2;
  int G = (ws_size > off) ? (int)((ws_size - off) / PSZ) : 1;
  if (G > NB) G = NB;
  if (G < 1) G = 1;
  u16* P = (u16*)alloc((size_t)G * PSZ);

  k_prep_w<<<(MR * CH + 255) / 256, 256, 0, stream>>>(wq, bq, wk, bk, wv, bv, Wb, biasS);
  k_convert<<<dim3(64, 8, NB), 256, 0, stream>>>(x, Xb, Xt);

  // QKV: [640][512] x [4096][512]^T  -> Vb, Qt, Kt (+bias)
  gemm_nt<EP_QKV><<<dim3(MR / 128, NPIX / 128, NB), 256, 0, stream>>>(
      Wb, Xt, 0L, (long)NPIX * CH, CH, CH, 0, Vb, Qt, Kt, biasS);

  // CA energy split-K: Xb x Xb^T, K=1024 per slice -> CAEp[b*4+ks]
  gemm_nt<EP_PART><<<dim3(CH / 128, CH / 128, NB * 4), 256, 0, stream>>>(
      Xb, Xb, (long)CH * NPIX, (long)CH * NPIX, 1024, NPIX, 0,
      CAEp, nullptr, nullptr, nullptr);
  k_ca_softmax<<<NB * CH / 4, 256, 0, stream>>>(CAEp, Aca);

  // PA, grouped by available scratch
  for (int b0 = 0; b0 < NB; b0 += G) {
    int gc = (NB - b0 < G) ? (NB - b0) : G;
    k_energy<<<dim3(NPIX / 64, 1, gc), 256, 0, stream>>>(Qt, Kt, P, rsum, b0);
    gemm_nt<EP_PV><<<dim3(CH / 128, NPIX / 128, gc), 256, 0, stream>>>(
        Vb + (size_t)b0 * CH * NPIX, P, (long)CH * NPIX, (long)NPIX * NPIX,
        NPIX, NPIX, b0, out, (void*)x, rsum, gpa);
  }

  // CA out: Aca x Xt^T (K=512), accumulate gca into out
  gemm_nt<EP_CA><<<dim3(CH / 128, NPIX / 128, NB), 256, 0, stream>>>(
      Aca, Xt, (long)CH * CH, (long)NPIX * CH, CH, CH, 0, out, nullptr, nullptr, gca);
}

// Round 3
// 236.406 us; speedup vs baseline: 1.5098x; 1.2146x over previous
//
// DANet dual-attention block, MI355X/gfx950.
// R3: flash-fused position attention (k_energy + PV GEMM -> one kernel).
//  - per block: (batch, 64-pixel n-tile); 8 waves; full C=512 owned per block
//  - QK^T swapped-operand mfma(K,Q) -> lane-local m-runs -> ds_write_b64 P_lds
//  - P_lds XOR-swizzled (T2), double-buffered -> ONE raw s_barrier per m-step
//  - V,K direct global->reg (no LDS), software prefetch one step ahead
//  - exp unnormalized (|E|<~7), 1/rowsum + gamma + 2x folded into epilogue
#include <hip/hip_runtime.h>

#define CH   512
#define NPIX 4096
#define CQ   32
#define MR   640   // 512 (wv) + 32 (wq) + 32 (wk) + 64 zero pad
#define NB   4

typedef unsigned short u16;
typedef __bf16 bf16x8 __attribute__((ext_vector_type(8)));
typedef float  f32x4  __attribute__((ext_vector_type(4)));
typedef unsigned int uint4v __attribute__((ext_vector_type(4)));
typedef unsigned int uint2v __attribute__((ext_vector_type(2)));

__device__ __forceinline__ u16 f2bf(float f) {
  union { float f; unsigned int u; } v; v.f = f;
  unsigned int r = v.u + 0x7FFFu + ((v.u >> 16) & 1u);   // RNE
  return (u16)(r >> 16);
}

__device__ __forceinline__ void gload_lds16(const u16* g, u16* l) {
  __builtin_amdgcn_global_load_lds(
      (const __attribute__((address_space(1))) unsigned int*)g,
      (__attribute__((address_space(3))) unsigned int*)l, 16, 0, 0);
}

__device__ __forceinline__ int xcd_swz(int flat, int nwg) {
  if (nwg & 7) return flat;
  return (flat & 7) * (nwg >> 3) + (flat >> 3);
}

// ---------------- weight stack: Wb[640][512] bf16, biasS[640] ----------------
__global__ void k_prep_w(const float* __restrict__ wq, const float* __restrict__ bq,
                         const float* __restrict__ wk, const float* __restrict__ bk,
                         const float* __restrict__ wv, const float* __restrict__ bv,
                         u16* __restrict__ Wb, float* __restrict__ biasS) {
  int idx = blockIdx.x * 256 + threadIdx.x;
  if (idx < MR * CH) {
    int r = idx >> 9, c = idx & 511;
    float v = 0.f;
    if (r < 512)      v = wv[r * CH + c];
    else if (r < 544) v = wq[(r - 512) * CH + c];
    else if (r < 576) v = wk[(r - 544) * CH + c];
    Wb[idx] = f2bf(v);
  }
  if (idx < MR) {
    float v = 0.f;
    if (idx < 512)      v = bv[idx];
    else if (idx < 544) v = bq[idx - 512];
    else if (idx < 576) v = bk[idx - 544];
    biasS[idx] = v;
  }
}

// ------------- x -> Xb bf16 [B][512][4096], Xt bf16 [B][4096][512] -----------
__global__ __launch_bounds__(256) void k_convert(const float* __restrict__ x,
                                                 u16* __restrict__ Xb,
                                                 u16* __restrict__ Xt) {
  __shared__ float tile[64][65];
  const int b = blockIdx.z, ct = blockIdx.y, nt = blockIdx.x;
  const int t = threadIdx.x, tn = t & 63, tg = t >> 6;
  const size_t xbase = ((size_t)b * CH + ct * 64) * NPIX + nt * 64;
#pragma unroll
  for (int i = 0; i < 16; ++i) {
    int cl = tg * 16 + i;
    float v = x[xbase + (size_t)cl * NPIX + tn];
    Xb[xbase + (size_t)cl * NPIX + tn] = f2bf(v);
    tile[cl][tn] = v;
  }
  __syncthreads();
  const size_t tbase = ((size_t)b * NPIX + nt * 64) * CH + ct * 64;
#pragma unroll
  for (int i = 0; i < 16; ++i) {
    int nl = tg * 16 + i;
    Xt[tbase + (size_t)nl * CH + tn] = f2bf(tile[tn][nl]);
  }
}

// --------------------------- generic NT bf16 GEMM ----------------------------
enum { EP_QKV = 0, EP_PART = 1, EP_CA = 3 };

template <int EP>
__global__ __launch_bounds__(256) void gemm_nt(
    const u16* __restrict__ Aall, const u16* __restrict__ Ball,
    long sA, long sB, int K, int ld, int zBase,
    void* pa0, void* pa1, void* pa2, const float* pg) {
  __shared__ u16 Alds[128 * 32];
  __shared__ u16 Blds[128 * 32];
  const int nbx = gridDim.x, nby = gridDim.y;
  const int nwg = nbx * nby * gridDim.z;
  int flat = blockIdx.x + nbx * (blockIdx.y + nby * blockIdx.z);
  flat = xcd_swz(flat, nwg);
  const int bx = flat % nbx, by = (flat / nbx) % nby, bz = flat / (nbx * nby);

  const int t = threadIdx.x, l = t & 63, w = t >> 6;
  const int wr = w >> 1, wc = w & 1;
  size_t aoff, boff;
  if constexpr (EP == EP_PART) {           // bz = b*4 + kslice
    aoff = (size_t)(bz >> 2) * sA + (size_t)(bz & 3) * 1024;
    boff = (size_t)(bz >> 2) * sB + (size_t)(bz & 3) * 1024;
  } else {
    aoff = (size_t)bz * sA;
    boff = (size_t)bz * sB;
  }
  const u16* A = Aall + aoff;
  const u16* B = Ball + boff;
  const int rowBase = bx * 128, colBase = by * 128;

  f32x4 acc[4][4];
#pragma unroll
  for (int i = 0; i < 4; ++i)
#pragma unroll
    for (int j = 0; j < 4; ++j) acc[i][j] = f32x4{0.f, 0.f, 0.f, 0.f};

  const int rs0 = l >> 2, cs0 = (l & 3) * 8;

  for (int k0 = 0; k0 < K; k0 += 32) {
    __syncthreads();
#pragma unroll
    for (int i = 0; i < 2; ++i) {
      int chunk = w * 2 + i;
      int r = chunk * 16 + rs0;
      gload_lds16(A + (size_t)(rowBase + r) * ld + k0 + cs0, Alds + chunk * 512);
      gload_lds16(B + (size_t)(colBase + r) * ld + k0 + cs0, Blds + chunk * 512);
    }
    __syncthreads();
    bf16x8 af[4], bfr[4];
#pragma unroll
    for (int i = 0; i < 4; ++i) {
      af[i]  = *(const bf16x8*)(Alds + (wr * 64 + i * 16 + (l & 15)) * 32 + (l >> 4) * 8);
      bfr[i] = *(const bf16x8*)(Blds + (wc * 64 + i * 16 + (l & 15)) * 32 + (l >> 4) * 8);
    }
#pragma unroll
    for (int i = 0; i < 4; ++i)
#pragma unroll
      for (int j = 0; j < 4; ++j)
        acc[i][j] = __builtin_amdgcn_mfma_f32_16x16x32_bf16(af[i], bfr[j], acc[i][j], 0, 0, 0);
  }

  // D layout: col = lane&15, row = (lane>>4)*4 + reg   [m89/m91 verified]
  const int b = zBase + bz;
  if constexpr (EP == EP_QKV) {
    u16* Vb = (u16*)pa0; u16* Qt = (u16*)pa1; u16* Kt = (u16*)pa2;
#pragma unroll
    for (int i = 0; i < 4; ++i)
#pragma unroll
      for (int r = 0; r < 4; ++r) {
        int row = rowBase + wr * 64 + i * 16 + (l >> 4) * 4 + r;
        if (row >= 576) continue;
        float bias = pg[row];
#pragma unroll
        for (int j = 0; j < 4; ++j) {
          int col = colBase + wc * 64 + j * 16 + (l & 15);
          u16 h = f2bf(acc[i][j][r] + bias);
          if (row < 512)      Vb[((size_t)b * CH + row) * NPIX + col] = h;
          else if (row < 544) Qt[((size_t)b * NPIX + col) * CQ + (row - 512)] = h;
          else                Kt[((size_t)b * NPIX + col) * CQ + (row - 544)] = h;
        }
      }
  } else if constexpr (EP == EP_PART) {    // CA energy partial, fp32 [bz][512][512]
    float* C = (float*)pa0;
#pragma unroll
    for (int i = 0; i < 4; ++i)
#pragma unroll
      for (int j = 0; j < 4; ++j)
#pragma unroll
        for (int r = 0; r < 4; ++r) {
          int row = rowBase + wr * 64 + i * 16 + (l >> 4) * 4 + r;
          int col = colBase + wc * 64 + j * 16 + (l & 15);
          C[((size_t)bz * CH + row) * CH + col] = acc[i][j][r];
        }
  } else {                                  // EP_CA: out += gca*acc
    float* out = (float*)pa0;
    const float gv = pg[0];
#pragma unroll
    for (int i = 0; i < 4; ++i)
#pragma unroll
      for (int j = 0; j < 4; ++j)
#pragma unroll
        for (int r = 0; r < 4; ++r) {
          int row = rowBase + wr * 64 + i * 16 + (l >> 4) * 4 + r;
          int col = colBase + wc * 64 + j * 16 + (l & 15);
          size_t idx = ((size_t)b * CH + row) * NPIX + col;
          out[idx] += gv * acc[i][j][r];
        }
  }
}

// ---------------- fused position attention (flash-style) ---------------------
// block: (batch b, 64-col n-tile). 8 waves; wave w owns c-rows [w*64, w*64+64).
// per m-step(64): QK^T swapped -> P_lds (swizzled, dbuf) -> PV with V in regs.
__global__ __launch_bounds__(512) void k_pa_fused(
    const u16* __restrict__ Qt, const u16* __restrict__ Kt,
    const u16* __restrict__ Vb, const float* __restrict__ x,
    float* __restrict__ out, const float* __restrict__ gpa) {
  __shared__ u16 Plds[2][64 * 64];        // [n][m] bf16, 16B-slot XOR swizzle
  __shared__ float rsums[8][16];

  int flat = xcd_swz(blockIdx.x, gridDim.x);
  const int b = flat >> 6, n0 = (flat & 63) * 64;
  const int t = threadIdx.x, l = t & 63, w = t >> 6;
  const int lo = l & 15, hi = l >> 4;
  const int nf = w >> 1;                   // this wave's QK^T n-frag
  const int mfb = (w & 1) * 2;             // its two m-frags: mfb, mfb+1

  const u16* Qtb = Qt + (size_t)b * NPIX * CQ;
  const u16* Ktb = Kt + (size_t)b * NPIX * CQ;
  const u16* Vbb = Vb + (size_t)b * CH * NPIX;

  const bf16x8 bq = *(const bf16x8*)(Qtb + (size_t)(n0 + nf * 16 + lo) * CQ + hi * 8);
  const f32x4 zero = {0.f, 0.f, 0.f, 0.f};

  f32x4 acc[4][4];
#pragma unroll
  for (int i = 0; i < 4; ++i)
#pragma unroll
    for (int j = 0; j < 4; ++j) acc[i][j] = zero;
  float rs = 0.f;

#define LDK(m, mf) (*(const bf16x8*)(Ktb + (size_t)((m) + (mf) * 16 + lo) * CQ + hi * 8))
#define LDV(m, i, h) (*(const bf16x8*)(Vbb + (size_t)(w * 64 + (i) * 16 + lo) * NPIX + (m) + (h) * 32 + hi * 8))

  // prologue: K(0), V(0) into set A
  bf16x8 kA0 = LDK(0, mfb), kA1 = LDK(0, mfb + 1);
  bf16x8 kB0, kB1;
  bf16x8 vA[8], vB[8];
#pragma unroll
  for (int i = 0; i < 4; ++i)
#pragma unroll
    for (int h = 0; h < 2; ++h) vA[i * 2 + h] = LDV(0, i, h);

#define PA_STEP(Kc0, Kc1, Vc, Kn0, Kn1, Vn, Pb, mnext)                          \
  {                                                                             \
    f32x4 s0 = __builtin_amdgcn_mfma_f32_16x16x32_bf16(Kc0, bq, zero, 0, 0, 0); \
    f32x4 s1 = __builtin_amdgcn_mfma_f32_16x16x32_bf16(Kc1, bq, zero, 0, 0, 0); \
    Kn0 = LDK(mnext, mfb);                                                      \
    Kn1 = LDK(mnext, mfb + 1);                                                  \
    const int n_ = nf * 16 + lo;                                                \
    _Pragma("unroll")                                                           \
    for (int i_ = 0; i_ < 2; ++i_) {                                            \
      f32x4 s = i_ ? s1 : s0;                                                   \
      float p0 = __expf(s[0]), p1 = __expf(s[1]);                               \
      float p2 = __expf(s[2]), p3 = __expf(s[3]);                               \
      rs += (p0 + p1) + (p2 + p3);                                              \
      unsigned int u0, u1;                                                      \
      asm("v_cvt_pk_bf16_f32 %0, %1, %2" : "=v"(u0) : "v"(p0), "v"(p1));        \
      asm("v_cvt_pk_bf16_f32 %0, %1, %2" : "=v"(u1) : "v"(p2), "v"(p3));        \
      int slot16_ = (mfb + i_) * 2 + (hi >> 1);                                 \
      char* dst_ = (char*)(Pb) + n_ * 128 + ((slot16_ ^ (n_ & 7)) << 4) +       \
                   (hi & 1) * 8;                                                \
      *(uint2v*)dst_ = uint2v{u0, u1};                                          \
    }                                                                           \
    asm volatile("s_waitcnt lgkmcnt(0)" ::: "memory");                          \
    __builtin_amdgcn_sched_barrier(0);                                          \
    __builtin_amdgcn_s_barrier();                                               \
    __builtin_amdgcn_sched_barrier(0);                                          \
    _Pragma("unroll")                                                           \
    for (int h_ = 0; h_ < 2; ++h_) {                                            \
      bf16x8 bp[4];                                                             \
      _Pragma("unroll")                                                         \
      for (int j_ = 0; j_ < 4; ++j_) {                                          \
        int nn_ = j_ * 16 + lo;                                                 \
        int sl_ = h_ * 4 + hi;                                                  \
        bp[j_] = *(const bf16x8*)((const char*)(Pb) + nn_ * 128 +               \
                                  ((sl_ ^ (nn_ & 7)) << 4));                    \
      }                                                                         \
      _Pragma("unroll")                                                         \
      for (int i_ = 0; i_ < 4; ++i_)                                            \
        _Pragma("unroll")                                                       \
        for (int j_ = 0; j_ < 4; ++j_)                                          \
          acc[i_][j_] = __builtin_amdgcn_mfma_f32_16x16x32_bf16(                \
              Vc[i_ * 2 + h_], bp[j_], acc[i_][j_], 0, 0, 0);                   \
    }                                                                           \
    _Pragma("unroll")                                                           \
    for (int i_ = 0; i_ < 4; ++i_)                                              \
      _Pragma("unroll")                                                         \
      for (int h_ = 0; h_ < 2; ++h_) Vn[i_ * 2 + h_] = LDV(mnext, i_, h_);      \
  }

  for (int ti = 0; ti < 64; ti += 2) {
    const int m1 = ti * 64 + 64;
    const int m2 = (ti * 64 + 128) & (NPIX - 1);
    PA_STEP(kA0, kA1, vA, kB0, kB1, vB, Plds[0], m1);
    PA_STEP(kB0, kB1, vB, kA0, kA1, vA, Plds[1], m2);
  }

  // rsum: reduce the 4 hi-groups, then pair waves (2nf, 2nf+1) via LDS
  rs += __shfl_xor(rs, 16);
  rs += __shfl_xor(rs, 32);
  if (l < 16) rsums[w][l] = rs;
  __syncthreads();
  float rinv[4];
#pragma unroll
  for (int j = 0; j < 4; ++j)
    rinv[j] = 1.0f / (rsums[2 * j][lo] + rsums[2 * j + 1][lo]);

  const float gv = gpa[0];
  float* outb = out + (size_t)b * CH * NPIX;
  const float* xb = x + (size_t)b * CH * NPIX;
#pragma unroll
  for (int i = 0; i < 4; ++i)
#pragma unroll
    for (int j = 0; j < 4; ++j)
#pragma unroll
      for (int r = 0; r < 4; ++r) {
        int c = w * 64 + i * 16 + hi * 4 + r;
        int n = n0 + j * 16 + lo;
        size_t idx = (size_t)c * NPIX + n;
        outb[idx] = gv * acc[i][j][r] * rinv[j] + 2.0f * xb[idx];
      }
#undef PA_STEP
#undef LDK
#undef LDV
}

// --- CA softmax: sum 4 split-K partials, Aca[row][d]=softmax_d(rowmax-E) -----
__global__ __launch_bounds__(256) void k_ca_softmax(const float* __restrict__ CAEp,
                                                    u16* __restrict__ Aca) {
  const int l = threadIdx.x & 63, w = threadIdx.x >> 6;
  const int row = blockIdx.x * 4 + w;   // [0, NB*512)
  const int b = row >> 9, r = row & 511;
  float en0[8];
#pragma unroll
  for (int i = 0; i < 8; ++i) en0[i] = 0.f;
#pragma unroll
  for (int ks = 0; ks < 4; ++ks) {
    const float* e = CAEp + (((size_t)(b * 4 + ks) * CH + r) * CH);
    f32x4 a = *(const f32x4*)(e + l * 8);
    f32x4 c = *(const f32x4*)(e + l * 8 + 4);
#pragma unroll
    for (int i = 0; i < 4; ++i) { en0[i] += a[i]; en0[4 + i] += c[i]; }
  }
  float m1 = en0[0];
#pragma unroll
  for (int i = 1; i < 8; ++i) m1 = fmaxf(m1, en0[i]);
  for (int o = 1; o < 64; o <<= 1) m1 = fmaxf(m1, __shfl_xor(m1, o));
  float en[8];
#pragma unroll
  for (int i = 0; i < 8; ++i) en[i] = m1 - en0[i];
  float m2 = en[0];
#pragma unroll
  for (int i = 1; i < 8; ++i) m2 = fmaxf(m2, en[i]);
  for (int o = 1; o < 64; o <<= 1) m2 = fmaxf(m2, __shfl_xor(m2, o));
  float p[8], s = 0.f;
#pragma unroll
  for (int i = 0; i < 8; ++i) { p[i] = __expf(en[i] - m2); s += p[i]; }
  for (int o = 1; o < 64; o <<= 1) s += __shfl_xor(s, o);
  const float inv = 1.0f / s;
  union { u16 h[8]; uint4v v; } u;
#pragma unroll
  for (int i = 0; i < 8; ++i) u.h[i] = f2bf(p[i] * inv);
  *(uint4v*)(Aca + (size_t)row * CH + l * 8) = u.v;
}

// --------------------------------- host --------------------------------------
extern "C" void kernel_launch(void* const* d_in, const int* in_sizes, int n_in,
                              void* d_out, int out_size, void* d_ws, size_t ws_size,
                              hipStream_t stream) {
  const float* x   = (const float*)d_in[0];
  const float* wq  = (const float*)d_in[1];
  const float* bq  = (const float*)d_in[2];
  const float* wk  = (const float*)d_in[3];
  const float* bk  = (const float*)d_in[4];
  const float* wv  = (const float*)d_in[5];
  const float* bv  = (const float*)d_in[6];
  const float* gpa = (const float*)d_in[7];
  const float* gca = (const float*)d_in[8];
  float* out = (float*)d_out;

  char* wsp = (char*)d_ws;
  size_t off = 0;
  auto alloc = [&](size_t bytes) -> void* {
    void* p = (void*)(wsp + off);
    off = (off + bytes + 255) & ~(size_t)255;
    return p;
  };
  const size_t EB = (size_t)NB * CH * NPIX;
  u16*   Xb    = (u16*)alloc(EB * 2);
  u16*   Xt    = (u16*)alloc(EB * 2);
  u16*   Wb    = (u16*)alloc((size_t)MR * CH * 2);
  float* biasS = (float*)alloc((size_t)MR * 4);
  u16*   Vb    = (u16*)alloc(EB * 2);
  u16*   Qt    = (u16*)alloc((size_t)NB * NPIX * CQ * 2);
  u16*   Kt    = (u16*)alloc((size_t)NB * NPIX * CQ * 2);
  float* CAEp  = (float*)alloc((size_t)NB * 4 * CH * CH * 4);   // split-K partials
  u16*   Aca   = (u16*)alloc((size_t)NB * CH * CH * 2);

  k_prep_w<<<(MR * CH + 255) / 256, 256, 0, stream>>>(wq, bq, wk, bk, wv, bv, Wb, biasS);
  k_convert<<<dim3(64, 8, NB), 256, 0, stream>>>(x, Xb, Xt);

  // QKV: [640][512] x [4096][512]^T  -> Vb, Qt, Kt (+bias)
  gemm_nt<EP_QKV><<<dim3(MR / 128, NPIX / 128, NB), 256, 0, stream>>>(
      Wb, Xt, 0L, (long)NPIX * CH, CH, CH, 0, Vb, Qt, Kt, biasS);

  // fused position attention -> out = gpa*PA + 2x
  k_pa_fused<<<NB * (NPIX / 64), 512, 0, stream>>>(Qt, Kt, Vb, x, out, gpa);

  // CA energy split-K: Xb x Xb^T, K=1024 per slice -> CAEp[b*4+ks]
  gemm_nt<EP_PART><<<dim3(CH / 128, CH / 128, NB * 4), 256, 0, stream>>>(
      Xb, Xb, (long)CH * NPIX, (long)CH * NPIX, 1024, NPIX, 0,
      CAEp, nullptr, nullptr, nullptr);
  k_ca_softmax<<<NB * CH / 4, 256, 0, stream>>>(CAEp, Aca);

  // CA out: Aca x Xt^T (K=512), accumulate gca into out
  gemm_nt<EP_CA><<<dim3(CH / 128, NPIX / 128, NB), 256, 0, stream>>>(
      Aca, Xt, (long)CH * CH, (long)NPIX * CH, CH, CH, 0, out, nullptr, nullptr, gca);
}

// Round 4
// 198.996 us; speedup vs baseline: 1.7936x; 1.1880x over previous
//
// DANet dual-attention block, MI355X/gfx950.
// R4: k_pa_fused V-staging via global_load_lds double-buffer + counted vmcnt
//     (T3/T4), per-wave-private swizzled V LDS (pre-swizzled global source,
//     rule #21), s_setprio around PV cluster (T5). Rest unchanged from R3.
#include <hip/hip_runtime.h>

#define CH   512
#define NPIX 4096
#define CQ   32
#define MR   640   // 512 (wv) + 32 (wq) + 32 (wk) + 64 zero pad
#define NB   4

typedef unsigned short u16;
typedef __bf16 bf16x8 __attribute__((ext_vector_type(8)));
typedef float  f32x4  __attribute__((ext_vector_type(4)));
typedef unsigned int uint4v __attribute__((ext_vector_type(4)));
typedef unsigned int uint2v __attribute__((ext_vector_type(2)));

__device__ __forceinline__ u16 f2bf(float f) {
  union { float f; unsigned int u; } v; v.f = f;
  unsigned int r = v.u + 0x7FFFu + ((v.u >> 16) & 1u);   // RNE
  return (u16)(r >> 16);
}

__device__ __forceinline__ void gload_lds16(const u16* g, u16* l) {
  __builtin_amdgcn_global_load_lds(
      (const __attribute__((address_space(1))) unsigned int*)g,
      (__attribute__((address_space(3))) unsigned int*)l, 16, 0, 0);
}

__device__ __forceinline__ int xcd_swz(int flat, int nwg) {
  if (nwg & 7) return flat;
  return (flat & 7) * (nwg >> 3) + (flat >> 3);
}

// ---------------- weight stack: Wb[640][512] bf16, biasS[640] ----------------
__global__ void k_prep_w(const float* __restrict__ wq, const float* __restrict__ bq,
                         const float* __restrict__ wk, const float* __restrict__ bk,
                         const float* __restrict__ wv, const float* __restrict__ bv,
                         u16* __restrict__ Wb, float* __restrict__ biasS) {
  int idx = blockIdx.x * 256 + threadIdx.x;
  if (idx < MR * CH) {
    int r = idx >> 9, c = idx & 511;
    float v = 0.f;
    if (r < 512)      v = wv[r * CH + c];
    else if (r < 544) v = wq[(r - 512) * CH + c];
    else if (r < 576) v = wk[(r - 544) * CH + c];
    Wb[idx] = f2bf(v);
  }
  if (idx < MR) {
    float v = 0.f;
    if (idx < 512)      v = bv[idx];
    else if (idx < 544) v = bq[idx - 512];
    else if (idx < 576) v = bk[idx - 544];
    biasS[idx] = v;
  }
}

// ------------- x -> Xb bf16 [B][512][4096], Xt bf16 [B][4096][512] -----------
__global__ __launch_bounds__(256) void k_convert(const float* __restrict__ x,
                                                 u16* __restrict__ Xb,
                                                 u16* __restrict__ Xt) {
  __shared__ float tile[64][65];
  const int b = blockIdx.z, ct = blockIdx.y, nt = blockIdx.x;
  const int t = threadIdx.x, tn = t & 63, tg = t >> 6;
  const size_t xbase = ((size_t)b * CH + ct * 64) * NPIX + nt * 64;
#pragma unroll
  for (int i = 0; i < 16; ++i) {
    int cl = tg * 16 + i;
    float v = x[xbase + (size_t)cl * NPIX + tn];
    Xb[xbase + (size_t)cl * NPIX + tn] = f2bf(v);
    tile[cl][tn] = v;
  }
  __syncthreads();
  const size_t tbase = ((size_t)b * NPIX + nt * 64) * CH + ct * 64;
#pragma unroll
  for (int i = 0; i < 16; ++i) {
    int nl = tg * 16 + i;
    Xt[tbase + (size_t)nl * CH + tn] = f2bf(tile[tn][nl]);
  }
}

// --------------------------- generic NT bf16 GEMM ----------------------------
enum { EP_QKV = 0, EP_PART = 1, EP_CA = 3 };

template <int EP>
__global__ __launch_bounds__(256) void gemm_nt(
    const u16* __restrict__ Aall, const u16* __restrict__ Ball,
    long sA, long sB, int K, int ld, int zBase,
    void* pa0, void* pa1, void* pa2, const float* pg) {
  __shared__ u16 Alds[128 * 32];
  __shared__ u16 Blds[128 * 32];
  const int nbx = gridDim.x, nby = gridDim.y;
  const int nwg = nbx * nby * gridDim.z;
  int flat = blockIdx.x + nbx * (blockIdx.y + nby * blockIdx.z);
  flat = xcd_swz(flat, nwg);
  const int bx = flat % nbx, by = (flat / nbx) % nby, bz = flat / (nbx * nby);

  const int t = threadIdx.x, l = t & 63, w = t >> 6;
  const int wr = w >> 1, wc = w & 1;
  size_t aoff, boff;
  if constexpr (EP == EP_PART) {           // bz = b*4 + kslice
    aoff = (size_t)(bz >> 2) * sA + (size_t)(bz & 3) * 1024;
    boff = (size_t)(bz >> 2) * sB + (size_t)(bz & 3) * 1024;
  } else {
    aoff = (size_t)bz * sA;
    boff = (size_t)bz * sB;
  }
  const u16* A = Aall + aoff;
  const u16* B = Ball + boff;
  const int rowBase = bx * 128, colBase = by * 128;

  f32x4 acc[4][4];
#pragma unroll
  for (int i = 0; i < 4; ++i)
#pragma unroll
    for (int j = 0; j < 4; ++j) acc[i][j] = f32x4{0.f, 0.f, 0.f, 0.f};

  const int rs0 = l >> 2, cs0 = (l & 3) * 8;

  for (int k0 = 0; k0 < K; k0 += 32) {
    __syncthreads();
#pragma unroll
    for (int i = 0; i < 2; ++i) {
      int chunk = w * 2 + i;
      int r = chunk * 16 + rs0;
      gload_lds16(A + (size_t)(rowBase + r) * ld + k0 + cs0, Alds + chunk * 512);
      gload_lds16(B + (size_t)(colBase + r) * ld + k0 + cs0, Blds + chunk * 512);
    }
    __syncthreads();
    bf16x8 af[4], bfr[4];
#pragma unroll
    for (int i = 0; i < 4; ++i) {
      af[i]  = *(const bf16x8*)(Alds + (wr * 64 + i * 16 + (l & 15)) * 32 + (l >> 4) * 8);
      bfr[i] = *(const bf16x8*)(Blds + (wc * 64 + i * 16 + (l & 15)) * 32 + (l >> 4) * 8);
    }
#pragma unroll
    for (int i = 0; i < 4; ++i)
#pragma unroll
      for (int j = 0; j < 4; ++j)
        acc[i][j] = __builtin_amdgcn_mfma_f32_16x16x32_bf16(af[i], bfr[j], acc[i][j], 0, 0, 0);
  }

  // D layout: col = lane&15, row = (lane>>4)*4 + reg   [m89/m91 verified]
  const int b = zBase + bz;
  if constexpr (EP == EP_QKV) {
    u16* Vb = (u16*)pa0; u16* Qt = (u16*)pa1; u16* Kt = (u16*)pa2;
#pragma unroll
    for (int i = 0; i < 4; ++i)
#pragma unroll
      for (int r = 0; r < 4; ++r) {
        int row = rowBase + wr * 64 + i * 16 + (l >> 4) * 4 + r;
        if (row >= 576) continue;
        float bias = pg[row];
#pragma unroll
        for (int j = 0; j < 4; ++j) {
          int col = colBase + wc * 64 + j * 16 + (l & 15);
          u16 h = f2bf(acc[i][j][r] + bias);
          if (row < 512)      Vb[((size_t)b * CH + row) * NPIX + col] = h;
          else if (row < 544) Qt[((size_t)b * NPIX + col) * CQ + (row - 512)] = h;
          else                Kt[((size_t)b * NPIX + col) * CQ + (row - 544)] = h;
        }
      }
  } else if constexpr (EP == EP_PART) {    // CA energy partial, fp32 [bz][512][512]
    float* C = (float*)pa0;
#pragma unroll
    for (int i = 0; i < 4; ++i)
#pragma unroll
      for (int j = 0; j < 4; ++j)
#pragma unroll
        for (int r = 0; r < 4; ++r) {
          int row = rowBase + wr * 64 + i * 16 + (l >> 4) * 4 + r;
          int col = colBase + wc * 64 + j * 16 + (l & 15);
          C[((size_t)bz * CH + row) * CH + col] = acc[i][j][r];
        }
  } else {                                  // EP_CA: out += gca*acc
    float* out = (float*)pa0;
    const float gv = pg[0];
#pragma unroll
    for (int i = 0; i < 4; ++i)
#pragma unroll
      for (int j = 0; j < 4; ++j)
#pragma unroll
        for (int r = 0; r < 4; ++r) {
          int row = rowBase + wr * 64 + i * 16 + (l >> 4) * 4 + r;
          int col = colBase + wc * 64 + j * 16 + (l & 15);
          size_t idx = ((size_t)b * CH + row) * NPIX + col;
          out[idx] += gv * acc[i][j][r];
        }
  }
}

// ---------------- fused position attention (flash-style) ---------------------
// block: (batch b, 64-col n-tile). 8 waves; wave w owns c-rows [w*64, w*64+64).
// per m-step(64): QK^T swapped -> P_lds (swizzled, dbuf, 1 barrier) -> PV with
// V staged in per-wave-private LDS via global_load_lds dbuf, counted vmcnt(10).
__global__ __launch_bounds__(512) void k_pa_fused(
    const u16* __restrict__ Qt, const u16* __restrict__ Kt,
    const u16* __restrict__ Vb, const float* __restrict__ x,
    float* __restrict__ out, const float* __restrict__ gpa) {
  __shared__ u16 Plds[2][64 * 64];        // 16 KB, [n][m] bf16, 16B-slot XOR swz
  __shared__ u16 Vlds[2][8][64 * 64];     // 128 KB, per-wave [64 c][64 m], XOR swz
  __shared__ float rsums[8][16];

  int flat = xcd_swz(blockIdx.x, gridDim.x);
  const int b = flat >> 6, n0 = (flat & 63) * 64;
  const int t = threadIdx.x, l = t & 63, w = t >> 6;
  const int lo = l & 15, hi = l >> 4;
  const int nf = w >> 1;                   // this wave's QK^T n-frag
  const int mfb = (w & 1) * 2;             // its two m-frags: mfb, mfb+1

  const u16* Qtb = Qt + (size_t)b * NPIX * CQ;
  const u16* Ktb = Kt + (size_t)b * NPIX * CQ;
  const u16* Vbb = Vb + (size_t)b * CH * NPIX;

  const bf16x8 bq = *(const bf16x8*)(Qtb + (size_t)(n0 + nf * 16 + lo) * CQ + hi * 8);
  const f32x4 zero = {0.f, 0.f, 0.f, 0.f};

  f32x4 acc[4][4];
#pragma unroll
  for (int i = 0; i < 4; ++i)
#pragma unroll
    for (int j = 0; j < 4; ++j) acc[i][j] = zero;
  float rs = 0.f;

  // V stage: lane l -> row (l>>3), global col pre-swizzled so LDS stays linear
  // while reads apply byte ^= ((row&7)<<4).  (rule #21: both-sides-or-neither)
  const int vcolsw = (((l & 7) ^ (l >> 3)) << 3);   // elements
  const u16* vsrc0 = Vbb + (size_t)(w * 64 + (l >> 3)) * NPIX + vcolsw;

#define LDK(m, mf) (*(const bf16x8*)(Ktb + (size_t)((m) + (mf) * 16 + lo) * CQ + hi * 8))
#define STAGE_V(mm, vb)                                                        \
  {                                                                            \
    u16* vbase_ = &Vlds[vb][w][0];                                             \
    const u16* gs_ = vsrc0 + (mm);                                             \
    _Pragma("unroll")                                                          \
    for (int s_ = 0; s_ < 8; ++s_)                                             \
      gload_lds16(gs_ + (size_t)s_ * 8 * NPIX, vbase_ + s_ * 512);             \
  }

  // prologue: K(0) regs, V(0) -> Vlds[0]
  bf16x8 kA0 = LDK(0, mfb), kA1 = LDK(0, mfb + 1);
  bf16x8 kB0, kB1;
  STAGE_V(0, 0);

#define PA_STEP(Kc0, Kc1, Kn0, Kn1, CUR, mnext)                                 \
  {                                                                             \
    f32x4 s0 = __builtin_amdgcn_mfma_f32_16x16x32_bf16(Kc0, bq, zero, 0, 0, 0); \
    f32x4 s1 = __builtin_amdgcn_mfma_f32_16x16x32_bf16(Kc1, bq, zero, 0, 0, 0); \
    Kn0 = LDK(mnext, mfb);                                                      \
    Kn1 = LDK(mnext, mfb + 1);                                                  \
    const int n_ = nf * 16 + lo;                                                \
    _Pragma("unroll")                                                           \
    for (int i_ = 0; i_ < 2; ++i_) {                                            \
      f32x4 s = i_ ? s1 : s0;                                                   \
      float p0 = __expf(s[0]), p1 = __expf(s[1]);                               \
      float p2 = __expf(s[2]), p3 = __expf(s[3]);                               \
      rs += (p0 + p1) + (p2 + p3);                                              \
      unsigned int u0, u1;                                                      \
      asm("v_cvt_pk_bf16_f32 %0, %1, %2" : "=v"(u0) : "v"(p0), "v"(p1));        \
      asm("v_cvt_pk_bf16_f32 %0, %1, %2" : "=v"(u1) : "v"(p2), "v"(p3));        \
      int slot16_ = (mfb + i_) * 2 + (hi >> 1);                                 \
      char* dst_ = (char*)(Plds[CUR]) + n_ * 128 +                              \
                   ((slot16_ ^ (n_ & 7)) << 4) + (hi & 1) * 8;                  \
      *(uint2v*)dst_ = uint2v{u0, u1};                                          \
    }                                                                           \
    asm volatile("s_waitcnt lgkmcnt(0)" ::: "memory");                          \
    __builtin_amdgcn_sched_barrier(0);                                          \
    __builtin_amdgcn_s_barrier();                                               \
    __builtin_amdgcn_sched_barrier(0);                                          \
    STAGE_V(mnext, CUR ^ 1);                                                    \
    asm volatile("s_waitcnt vmcnt(10)" ::: "memory");                           \
    __builtin_amdgcn_sched_barrier(0);                                          \
    __builtin_amdgcn_s_setprio(1);                                              \
    _Pragma("unroll")                                                           \
    for (int h_ = 0; h_ < 2; ++h_) {                                            \
      bf16x8 va[4], bp[4];                                                      \
      _Pragma("unroll")                                                         \
      for (int i_ = 0; i_ < 4; ++i_) {                                          \
        int vr_ = i_ * 16 + lo;                                                 \
        va[i_] = *(const bf16x8*)((const char*)(&Vlds[CUR][w][0]) + vr_ * 128 + \
                                  ((h_ * 64 + hi * 16) ^ ((lo & 7) << 4)));     \
      }                                                                         \
      _Pragma("unroll")                                                         \
      for (int j_ = 0; j_ < 4; ++j_) {                                          \
        int nn_ = j_ * 16 + lo;                                                 \
        int sl_ = h_ * 4 + hi;                                                  \
        bp[j_] = *(const bf16x8*)((const char*)(Plds[CUR]) + nn_ * 128 +        \
                                  ((sl_ ^ (nn_ & 7)) << 4));                    \
      }                                                                         \
      _Pragma("unroll")                                                         \
      for (int i_ = 0; i_ < 4; ++i_)                                            \
        _Pragma("unroll")                                                       \
        for (int j_ = 0; j_ < 4; ++j_)                                          \
          acc[i_][j_] = __builtin_amdgcn_mfma_f32_16x16x32_bf16(                \
              va[i_], bp[j_], acc[i_][j_], 0, 0, 0);                            \
    }                                                                           \
    __builtin_amdgcn_s_setprio(0);                                              \
  }

  for (int ti = 0; ti < 64; ti += 2) {
    PA_STEP(kA0, kA1, kB0, kB1, 0, (((ti + 1) & 63) * 64));
    PA_STEP(kB0, kB1, kA0, kA1, 1, (((ti + 2) & 63) * 64));
  }

  // rsum: reduce the 4 hi-groups, then pair waves (2nf, 2nf+1) via LDS
  rs += __shfl_xor(rs, 16);
  rs += __shfl_xor(rs, 32);
  if (l < 16) rsums[w][l] = rs;
  __syncthreads();
  float rinv[4];
#pragma unroll
  for (int j = 0; j < 4; ++j)
    rinv[j] = 1.0f / (rsums[2 * j][lo] + rsums[2 * j + 1][lo]);

  const float gv = gpa[0];
  float* outb = out + (size_t)b * CH * NPIX;
  const float* xb = x + (size_t)b * CH * NPIX;
#pragma unroll
  for (int i = 0; i < 4; ++i)
#pragma unroll
    for (int j = 0; j < 4; ++j)
#pragma unroll
      for (int r = 0; r < 4; ++r) {
        int c = w * 64 + i * 16 + hi * 4 + r;
        int n = n0 + j * 16 + lo;
        size_t idx = (size_t)c * NPIX + n;
        outb[idx] = gv * acc[i][j][r] * rinv[j] + 2.0f * xb[idx];
      }
#undef PA_STEP
#undef STAGE_V
#undef LDK
}

// --- CA softmax: sum 4 split-K partials, Aca[row][d]=softmax_d(rowmax-E) -----
__global__ __launch_bounds__(256) void k_ca_softmax(const float* __restrict__ CAEp,
                                                    u16* __restrict__ Aca) {
  const int l = threadIdx.x & 63, w = threadIdx.x >> 6;
  const int row = blockIdx.x * 4 + w;   // [0, NB*512)
  const int b = row >> 9, r = row & 511;
  float en0[8];
#pragma unroll
  for (int i = 0; i < 8; ++i) en0[i] = 0.f;
#pragma unroll
  for (int ks = 0; ks < 4; ++ks) {
    const float* e = CAEp + (((size_t)(b * 4 + ks) * CH + r) * CH);
    f32x4 a = *(const f32x4*)(e + l * 8);
    f32x4 c = *(const f32x4*)(e + l * 8 + 4);
#pragma unroll
    for (int i = 0; i < 4; ++i) { en0[i] += a[i]; en0[4 + i] += c[i]; }
  }
  float m1 = en0[0];
#pragma unroll
  for (int i = 1; i < 8; ++i) m1 = fmaxf(m1, en0[i]);
  for (int o = 1; o < 64; o <<= 1) m1 = fmaxf(m1, __shfl_xor(m1, o));
  float en[8];
#pragma unroll
  for (int i = 0; i < 8; ++i) en[i] = m1 - en0[i];
  float m2 = en[0];
#pragma unroll
  for (int i = 1; i < 8; ++i) m2 = fmaxf(m2, en[i]);
  for (int o = 1; o < 64; o <<= 1) m2 = fmaxf(m2, __shfl_xor(m2, o));
  float p[8], s = 0.f;
#pragma unroll
  for (int i = 0; i < 8; ++i) { p[i] = __expf(en[i] - m2); s += p[i]; }
  for (int o = 1; o < 64; o <<= 1) s += __shfl_xor(s, o);
  const float inv = 1.0f / s;
  union { u16 h[8]; uint4v v; } u;
#pragma unroll
  for (int i = 0; i < 8; ++i) u.h[i] = f2bf(p[i] * inv);
  *(uint4v*)(Aca + (size_t)row * CH + l * 8) = u.v;
}

// --------------------------------- host --------------------------------------
extern "C" void kernel_launch(void* const* d_in, const int* in_sizes, int n_in,
                              void* d_out, int out_size, void* d_ws, size_t ws_size,
                              hipStream_t stream) {
  const float* x   = (const float*)d_in[0];
  const float* wq  = (const float*)d_in[1];
  const float* bq  = (const float*)d_in[2];
  const float* wk  = (const float*)d_in[3];
  const float* bk  = (const float*)d_in[4];
  const float* wv  = (const float*)d_in[5];
  const float* bv  = (const float*)d_in[6];
  const float* gpa = (const float*)d_in[7];
  const float* gca = (const float*)d_in[8];
  float* out = (float*)d_out;

  char* wsp = (char*)d_ws;
  size_t off = 0;
  auto alloc = [&](size_t bytes) -> void* {
    void* p = (void*)(wsp + off);
    off = (off + bytes + 255) & ~(size_t)255;
    return p;
  };
  const size_t EB = (size_t)NB * CH * NPIX;
  u16*   Xb    = (u16*)alloc(EB * 2);
  u16*   Xt    = (u16*)alloc(EB * 2);
  u16*   Wb    = (u16*)alloc((size_t)MR * CH * 2);
  float* biasS = (float*)alloc((size_t)MR * 4);
  u16*   Vb    = (u16*)alloc(EB * 2);
  u16*   Qt    = (u16*)alloc((size_t)NB * NPIX * CQ * 2);
  u16*   Kt    = (u16*)alloc((size_t)NB * NPIX * CQ * 2);
  float* CAEp  = (float*)alloc((size_t)NB * 4 * CH * CH * 4);   // split-K partials
  u16*   Aca   = (u16*)alloc((size_t)NB * CH * CH * 2);

  k_prep_w<<<(MR * CH + 255) / 256, 256, 0, stream>>>(wq, bq, wk, bk, wv, bv, Wb, biasS);
  k_convert<<<dim3(64, 8, NB), 256, 0, stream>>>(x, Xb, Xt);

  // QKV: [640][512] x [4096][512]^T  -> Vb, Qt, Kt (+bias)
  gemm_nt<EP_QKV><<<dim3(MR / 128, NPIX / 128, NB), 256, 0, stream>>>(
      Wb, Xt, 0L, (long)NPIX * CH, CH, CH, 0, Vb, Qt, Kt, biasS);

  // fused position attention -> out = gpa*PA + 2x
  k_pa_fused<<<NB * (NPIX / 64), 512, 0, stream>>>(Qt, Kt, Vb, x, out, gpa);

  // CA energy split-K: Xb x Xb^T, K=1024 per slice -> CAEp[b*4+ks]
  gemm_nt<EP_PART><<<dim3(CH / 128, CH / 128, NB * 4), 256, 0, stream>>>(
      Xb, Xb, (long)CH * NPIX, (long)CH * NPIX, 1024, NPIX, 0,
      CAEp, nullptr, nullptr, nullptr);
  k_ca_softmax<<<NB * CH / 4, 256, 0, stream>>>(CAEp, Aca);

  // CA out: Aca x Xt^T (K=512), accumulate gca into out
  gemm_nt<EP_CA><<<dim3(CH / 128, NPIX / 128, NB), 256, 0, stream>>>(
      Aca, Xt, (long)CH * CH, (long)NPIX * CH, CH, CH, 0, out, nullptr, nullptr, gca);
}

// Round 5
// 183.004 us; speedup vs baseline: 1.9504x; 1.0874x over previous
//
// DANet dual-attention block, MI355X/gfx950.
// R5: pa_fused -> c-split 4-wave blocks (grid 512, 2 indep blocks/CU),
//     column-assigned QK^T (K redundancy 4x->1x, Q hoisted), P single-buffer
//     2-barrier step, V dbuf via global_load_lds + vmcnt(9);
//     CA-out GEMM folded into pa_fused epilogue (Aca pre-scaled by gamma_ca).
#include <hip/hip_runtime.h>

#define CH   512
#define NPIX 4096
#define CQ   32
#define MR   640   // 512 (wv) + 32 (wq) + 32 (wk) + 64 zero pad
#define NB   4

typedef unsigned short u16;
typedef __bf16 bf16x8 __attribute__((ext_vector_type(8)));
typedef float  f32x4  __attribute__((ext_vector_type(4)));
typedef unsigned int uint4v __attribute__((ext_vector_type(4)));
typedef unsigned int uint2v __attribute__((ext_vector_type(2)));

__device__ __forceinline__ u16 f2bf(float f) {
  union { float f; unsigned int u; } v; v.f = f;
  unsigned int r = v.u + 0x7FFFu + ((v.u >> 16) & 1u);   // RNE
  return (u16)(r >> 16);
}

__device__ __forceinline__ void gload_lds16(const u16* g, u16* l) {
  __builtin_amdgcn_global_load_lds(
      (const __attribute__((address_space(1))) unsigned int*)g,
      (__attribute__((address_space(3))) unsigned int*)l, 16, 0, 0);
}

__device__ __forceinline__ int xcd_swz(int flat, int nwg) {
  if (nwg & 7) return flat;
  return (flat & 7) * (nwg >> 3) + (flat >> 3);
}

// ---------------- weight stack: Wb[640][512] bf16, biasS[640] ----------------
__global__ void k_prep_w(const float* __restrict__ wq, const float* __restrict__ bq,
                         const float* __restrict__ wk, const float* __restrict__ bk,
                         const float* __restrict__ wv, const float* __restrict__ bv,
                         u16* __restrict__ Wb, float* __restrict__ biasS) {
  int idx = blockIdx.x * 256 + threadIdx.x;
  if (idx < MR * CH) {
    int r = idx >> 9, c = idx & 511;
    float v = 0.f;
    if (r < 512)      v = wv[r * CH + c];
    else if (r < 544) v = wq[(r - 512) * CH + c];
    else if (r < 576) v = wk[(r - 544) * CH + c];
    Wb[idx] = f2bf(v);
  }
  if (idx < MR) {
    float v = 0.f;
    if (idx < 512)      v = bv[idx];
    else if (idx < 544) v = bq[idx - 512];
    else if (idx < 576) v = bk[idx - 544];
    biasS[idx] = v;
  }
}

// ------------- x -> Xb bf16 [B][512][4096], Xt bf16 [B][4096][512] -----------
__global__ __launch_bounds__(256) void k_convert(const float* __restrict__ x,
                                                 u16* __restrict__ Xb,
                                                 u16* __restrict__ Xt) {
  __shared__ float tile[64][65];
  const int b = blockIdx.z, ct = blockIdx.y, nt = blockIdx.x;
  const int t = threadIdx.x, tn = t & 63, tg = t >> 6;
  const size_t xbase = ((size_t)b * CH + ct * 64) * NPIX + nt * 64;
#pragma unroll
  for (int i = 0; i < 16; ++i) {
    int cl = tg * 16 + i;
    float v = x[xbase + (size_t)cl * NPIX + tn];
    Xb[xbase + (size_t)cl * NPIX + tn] = f2bf(v);
    tile[cl][tn] = v;
  }
  __syncthreads();
  const size_t tbase = ((size_t)b * NPIX + nt * 64) * CH + ct * 64;
#pragma unroll
  for (int i = 0; i < 16; ++i) {
    int nl = tg * 16 + i;
    Xt[tbase + (size_t)nl * CH + tn] = f2bf(tile[tn][nl]);
  }
}

// --------------------------- generic NT bf16 GEMM ----------------------------
enum { EP_QKV = 0, EP_PART = 1 };

template <int EP>
__global__ __launch_bounds__(256) void gemm_nt(
    const u16* __restrict__ Aall, const u16* __restrict__ Ball,
    long sA, long sB, int K, int ld, int zBase,
    void* pa0, void* pa1, void* pa2, const float* pg) {
  __shared__ u16 Alds[128 * 32];
  __shared__ u16 Blds[128 * 32];
  const int nbx = gridDim.x, nby = gridDim.y;
  const int nwg = nbx * nby * gridDim.z;
  int flat = blockIdx.x + nbx * (blockIdx.y + nby * blockIdx.z);
  flat = xcd_swz(flat, nwg);
  const int bx = flat % nbx, by = (flat / nbx) % nby, bz = flat / (nbx * nby);

  const int t = threadIdx.x, l = t & 63, w = t >> 6;
  const int wr = w >> 1, wc = w & 1;
  size_t aoff, boff;
  if constexpr (EP == EP_PART) {           // bz = b*4 + kslice
    aoff = (size_t)(bz >> 2) * sA + (size_t)(bz & 3) * 1024;
    boff = (size_t)(bz >> 2) * sB + (size_t)(bz & 3) * 1024;
  } else {
    aoff = (size_t)bz * sA;
    boff = (size_t)bz * sB;
  }
  const u16* A = Aall + aoff;
  const u16* B = Ball + boff;
  const int rowBase = bx * 128, colBase = by * 128;

  f32x4 acc[4][4];
#pragma unroll
  for (int i = 0; i < 4; ++i)
#pragma unroll
    for (int j = 0; j < 4; ++j) acc[i][j] = f32x4{0.f, 0.f, 0.f, 0.f};

  const int rs0 = l >> 2, cs0 = (l & 3) * 8;

  for (int k0 = 0; k0 < K; k0 += 32) {
    __syncthreads();
#pragma unroll
    for (int i = 0; i < 2; ++i) {
      int chunk = w * 2 + i;
      int r = chunk * 16 + rs0;
      gload_lds16(A + (size_t)(rowBase + r) * ld + k0 + cs0, Alds + chunk * 512);
      gload_lds16(B + (size_t)(colBase + r) * ld + k0 + cs0, Blds + chunk * 512);
    }
    __syncthreads();
    bf16x8 af[4], bfr[4];
#pragma unroll
    for (int i = 0; i < 4; ++i) {
      af[i]  = *(const bf16x8*)(Alds + (wr * 64 + i * 16 + (l & 15)) * 32 + (l >> 4) * 8);
      bfr[i] = *(const bf16x8*)(Blds + (wc * 64 + i * 16 + (l & 15)) * 32 + (l >> 4) * 8);
    }
#pragma unroll
    for (int i = 0; i < 4; ++i)
#pragma unroll
      for (int j = 0; j < 4; ++j)
        acc[i][j] = __builtin_amdgcn_mfma_f32_16x16x32_bf16(af[i], bfr[j], acc[i][j], 0, 0, 0);
  }

  // D layout: col = lane&15, row = (lane>>4)*4 + reg   [m89/m91 verified]
  const int b = zBase + bz;
  if constexpr (EP == EP_QKV) {
    u16* Vb = (u16*)pa0; u16* Qt = (u16*)pa1; u16* Kt = (u16*)pa2;
#pragma unroll
    for (int i = 0; i < 4; ++i)
#pragma unroll
      for (int r = 0; r < 4; ++r) {
        int row = rowBase + wr * 64 + i * 16 + (l >> 4) * 4 + r;
        if (row >= 576) continue;
        float bias = pg[row];
#pragma unroll
        for (int j = 0; j < 4; ++j) {
          int col = colBase + wc * 64 + j * 16 + (l & 15);
          u16 h = f2bf(acc[i][j][r] + bias);
          if (row < 512)      Vb[((size_t)b * CH + row) * NPIX + col] = h;
          else if (row < 544) Qt[((size_t)b * NPIX + col) * CQ + (row - 512)] = h;
          else                Kt[((size_t)b * NPIX + col) * CQ + (row - 544)] = h;
        }
      }
  } else {                                 // EP_PART: CA energy partial fp32
    float* C = (float*)pa0;
#pragma unroll
    for (int i = 0; i < 4; ++i)
#pragma unroll
      for (int j = 0; j < 4; ++j)
#pragma unroll
        for (int r = 0; r < 4; ++r) {
          int row = rowBase + wr * 64 + i * 16 + (l >> 4) * 4 + r;
          int col = colBase + wc * 64 + j * 16 + (l & 15);
          C[((size_t)bz * CH + row) * CH + col] = acc[i][j][r];
        }
  }
}

// ---------------- fused position attention + CA-out epilogue -----------------
// block: (batch, n-tile 64, c-half 256); 4 waves, wave w owns c-rows
// [chalf*256 + w*64, +64).  QK^T column-assigned: wave w computes m-frag w for
// all 4 n-frags (K loaded once per step per wave; Q hoisted).  P single-buffer
// (2 barriers/step); V dbuf via global_load_lds, counted vmcnt(9).
// Epilogue: acc = gpa*PV/rowsum, then acc += Aca_scaled x Xt^T (K=512), then
// out = acc + 2x.
__global__ __launch_bounds__(256, 2) void k_pa_fused(
    const u16* __restrict__ Qt, const u16* __restrict__ Kt,
    const u16* __restrict__ Vb, const u16* __restrict__ Aca,
    const u16* __restrict__ Xt, const float* __restrict__ x,
    float* __restrict__ out, const float* __restrict__ gpa) {
  __shared__ u16 Plds[64 * 64];           // 8 KB; later rsum buf + CA Xt tile
  __shared__ u16 Vlds[2][4][64 * 64];     // 64 KB; Vlds[0] later CA A tile
  int flat = xcd_swz(blockIdx.x, gridDim.x);
  const int chalf = flat & 1, nt = (flat >> 1) & 63, b = flat >> 7;
  const int n0 = nt * 64;
  const int l = threadIdx.x & 63, w = threadIdx.x >> 6;
  const int lo = l & 15, hi = l >> 4;
  const int c0w = chalf * 256 + w * 64;

  const u16* Qtb = Qt + (size_t)b * NPIX * CQ;
  const u16* Ktb = Kt + (size_t)b * NPIX * CQ;
  const u16* Vbb = Vb + (size_t)b * CH * NPIX;
  const f32x4 zero = {0.f, 0.f, 0.f, 0.f};

  // hoisted Q fragments (loop-invariant): all 4 n-frags
  bf16x8 bq[4];
#pragma unroll
  for (int nf = 0; nf < 4; ++nf)
    bq[nf] = *(const bf16x8*)(Qtb + (size_t)(n0 + nf * 16 + lo) * CQ + hi * 8);

  f32x4 acc[4][4];
#pragma unroll
  for (int i = 0; i < 4; ++i)
#pragma unroll
    for (int j = 0; j < 4; ++j) acc[i][j] = zero;
  float rs[4] = {0.f, 0.f, 0.f, 0.f};

  // V staging: lane l -> c-row (l>>3), global col pre-swizzled (rule #21)
  const int vcolsw = (((l & 7) ^ (l >> 3)) << 3);
  const u16* vsrc0 = Vbb + (size_t)(c0w + (l >> 3)) * NPIX + vcolsw;

#define LDK(m) (*(const bf16x8*)(Ktb + (size_t)((m) + w * 16 + lo) * CQ + hi * 8))
#define STAGE_V(mm, X)                                                         \
  {                                                                            \
    u16* vb_ = &Vlds[X][w][0];                                                 \
    const u16* g_ = vsrc0 + (mm);                                              \
    _Pragma("unroll")                                                          \
    for (int s_ = 0; s_ < 8; ++s_)                                             \
      gload_lds16(g_ + (size_t)s_ * 8 * NPIX, vb_ + s_ * 512);                 \
  }

  bf16x8 kc = LDK(0), kn;
  STAGE_V(0, 0);
  const int pslot = w * 2 + (hi >> 1);

  for (int ti = 0; ti < 64; ++ti) {
    const int X = ti & 1;
    const int mnext = ((ti + 1) & 63) * 64;
    // QK^T: wave w = m-frag w, all n-frags
    f32x4 s[4];
#pragma unroll
    for (int nf = 0; nf < 4; ++nf)
      s[nf] = __builtin_amdgcn_mfma_f32_16x16x32_bf16(kc, bq[nf], zero, 0, 0, 0);
    kn = LDK(mnext);
    unsigned int uu[4][2];
#pragma unroll
    for (int nf = 0; nf < 4; ++nf) {
      float p0 = __expf(s[nf][0]), p1 = __expf(s[nf][1]);
      float p2 = __expf(s[nf][2]), p3 = __expf(s[nf][3]);
      rs[nf] += (p0 + p1) + (p2 + p3);
      asm("v_cvt_pk_bf16_f32 %0, %1, %2" : "=v"(uu[nf][0]) : "v"(p0), "v"(p1));
      asm("v_cvt_pk_bf16_f32 %0, %1, %2" : "=v"(uu[nf][1]) : "v"(p2), "v"(p3));
    }
    __builtin_amdgcn_s_barrier();                 // BAR1: prev P reads done
    __builtin_amdgcn_sched_barrier(0);
#pragma unroll
    for (int nf = 0; nf < 4; ++nf) {
      int n_ = nf * 16 + lo;
      char* dst_ = (char*)Plds + n_ * 128 + ((pslot ^ (n_ & 7)) << 4) + (hi & 1) * 8;
      *(uint2v*)dst_ = uint2v{uu[nf][0], uu[nf][1]};
    }
    asm volatile("s_waitcnt lgkmcnt(0)" ::: "memory");
    __builtin_amdgcn_sched_barrier(0);
    __builtin_amdgcn_s_barrier();                 // BAR2: P ready
    __builtin_amdgcn_sched_barrier(0);
    STAGE_V(mnext, X ^ 1);
    asm volatile("s_waitcnt vmcnt(9)" ::: "memory");   // V(ti) landed; V(ti+1)+K in flight
    __builtin_amdgcn_sched_barrier(0);
    __builtin_amdgcn_s_setprio(1);
#pragma unroll
    for (int h = 0; h < 2; ++h) {
      bf16x8 va[4], bp[4];
#pragma unroll
      for (int i = 0; i < 4; ++i) {
        int vr = i * 16 + lo;
        va[i] = *(const bf16x8*)((const char*)(&Vlds[X][w][0]) + vr * 128 +
                                 ((h * 64 + hi * 16) ^ ((lo & 7) << 4)));
      }
#pragma unroll
      for (int j = 0; j < 4; ++j) {
        int nn = j * 16 + lo;
        bp[j] = *(const bf16x8*)((const char*)Plds + nn * 128 +
                                 (((h * 4 + hi) ^ (nn & 7)) << 4));
      }
#pragma unroll
      for (int i = 0; i < 4; ++i)
#pragma unroll
        for (int j = 0; j < 4; ++j)
          acc[i][j] = __builtin_amdgcn_mfma_f32_16x16x32_bf16(va[i], bp[j], acc[i][j], 0, 0, 0);
    }
    __builtin_amdgcn_s_setprio(0);
    kc = kn;
  }
#undef STAGE_V
#undef LDK

  // ---- rowsum exchange (reuse Plds) ----
  __syncthreads();
#pragma unroll
  for (int nf = 0; nf < 4; ++nf) {
    rs[nf] += __shfl_xor(rs[nf], 16);
    rs[nf] += __shfl_xor(rs[nf], 32);
  }
  float* rbuf = (float*)Plds;
  if (l < 16) {
#pragma unroll
    for (int nf = 0; nf < 4; ++nf) rbuf[w * 64 + nf * 16 + l] = rs[nf];
  }
  __syncthreads();
  const float gv = gpa[0];
  float rinv[4];
#pragma unroll
  for (int j = 0; j < 4; ++j)
    rinv[j] = gv / (rbuf[j * 16 + lo] + rbuf[64 + j * 16 + lo] +
                    rbuf[128 + j * 16 + lo] + rbuf[192 + j * 16 + lo]);
#pragma unroll
  for (int i = 0; i < 4; ++i)
#pragma unroll
    for (int j = 0; j < 4; ++j) acc[i][j] *= rinv[j];
  __syncthreads();   // rinv read done; Plds/Vlds reusable for CA staging

  // ---- CA-out epilogue: acc += Aca_scaled[c,:] x Xt[n,:]^T  (K=512) ----
  const u16* Acab = Aca + (size_t)b * CH * CH;
  const u16* Xtb = Xt + (size_t)b * NPIX * CH;
  const int ar = l >> 2;
  const int acs = (((l & 3) ^ (ar & 3)) << 3);   // pre-swizzled k-col (elems)
  u16* aldsw = &Vlds[0][w][0];                   // per-wave [64][32] A tile
  u16* xlds = &Plds[0];                          // [64][32] Xt tile

  for (int k0 = 0; k0 < CH; k0 += 32) {
    __syncthreads();
#pragma unroll
    for (int cch = 0; cch < 4; ++cch)
      gload_lds16(Acab + (size_t)(c0w + cch * 16 + ar) * CH + k0 + acs,
                  aldsw + cch * 512);
    gload_lds16(Xtb + (size_t)(n0 + w * 16 + ar) * CH + k0 + acs, xlds + w * 512);
    __syncthreads();
    bf16x8 af[4], bfx[4];
#pragma unroll
    for (int i = 0; i < 4; ++i) {
      int r = i * 16 + lo;
      af[i] = *(const bf16x8*)((const char*)aldsw + r * 64 + ((hi ^ (r & 3)) << 4));
    }
#pragma unroll
    for (int j = 0; j < 4; ++j) {
      int nn = j * 16 + lo;
      bfx[j] = *(const bf16x8*)((const char*)xlds + nn * 64 + ((hi ^ (nn & 3)) << 4));
    }
#pragma unroll
    for (int i = 0; i < 4; ++i)
#pragma unroll
      for (int j = 0; j < 4; ++j)
        acc[i][j] = __builtin_amdgcn_mfma_f32_16x16x32_bf16(af[i], bfx[j], acc[i][j], 0, 0, 0);
  }

  // ---- final: out = acc + 2x ----
  float* outb = out + (size_t)b * CH * NPIX;
  const float* xb = x + (size_t)b * CH * NPIX;
#pragma unroll
  for (int i = 0; i < 4; ++i)
#pragma unroll
    for (int j = 0; j < 4; ++j)
#pragma unroll
      for (int r = 0; r < 4; ++r) {
        int c = c0w + i * 16 + hi * 4 + r;
        int n = n0 + j * 16 + lo;
        size_t idx = (size_t)c * NPIX + n;
        outb[idx] = acc[i][j][r] + 2.0f * xb[idx];
      }
}

// --- CA softmax: sum 4 split-K partials; Aca = gca * softmax_d(rowmax-E) -----
__global__ __launch_bounds__(256) void k_ca_softmax(const float* __restrict__ CAEp,
                                                    u16* __restrict__ Aca,
                                                    const float* __restrict__ gca) {
  const int l = threadIdx.x & 63, w = threadIdx.x >> 6;
  const int row = blockIdx.x * 4 + w;   // [0, NB*512)
  const int b = row >> 9, r = row & 511;
  float en0[8];
#pragma unroll
  for (int i = 0; i < 8; ++i) en0[i] = 0.f;
#pragma unroll
  for (int ks = 0; ks < 4; ++ks) {
    const float* e = CAEp + (((size_t)(b * 4 + ks) * CH + r) * CH);
    f32x4 a = *(const f32x4*)(e + l * 8);
    f32x4 c = *(const f32x4*)(e + l * 8 + 4);
#pragma unroll
    for (int i = 0; i < 4; ++i) { en0[i] += a[i]; en0[4 + i] += c[i]; }
  }
  float m1 = en0[0];
#pragma unroll
  for (int i = 1; i < 8; ++i) m1 = fmaxf(m1, en0[i]);
  for (int o = 1; o < 64; o <<= 1) m1 = fmaxf(m1, __shfl_xor(m1, o));
  float en[8];
#pragma unroll
  for (int i = 0; i < 8; ++i) en[i] = m1 - en0[i];
  float m2 = en[0];
#pragma unroll
  for (int i = 1; i < 8; ++i) m2 = fmaxf(m2, en[i]);
  for (int o = 1; o < 64; o <<= 1) m2 = fmaxf(m2, __shfl_xor(m2, o));
  float p[8], s = 0.f;
#pragma unroll
  for (int i = 0; i < 8; ++i) { p[i] = __expf(en[i] - m2); s += p[i]; }
  for (int o = 1; o < 64; o <<= 1) s += __shfl_xor(s, o);
  const float inv = gca[0] / s;
  union { u16 h[8]; uint4v v; } u;
#pragma unroll
  for (int i = 0; i < 8; ++i) u.h[i] = f2bf(p[i] * inv);
  *(uint4v*)(Aca + (size_t)row * CH + l * 8) = u.v;
}

// --------------------------------- host --------------------------------------
extern "C" void kernel_launch(void* const* d_in, const int* in_sizes, int n_in,
                              void* d_out, int out_size, void* d_ws, size_t ws_size,
                              hipStream_t stream) {
  const float* x   = (const float*)d_in[0];
  const float* wq  = (const float*)d_in[1];
  const float* bq  = (const float*)d_in[2];
  const float* wk  = (const float*)d_in[3];
  const float* bk  = (const float*)d_in[4];
  const float* wv  = (const float*)d_in[5];
  const float* bv  = (const float*)d_in[6];
  const float* gpa = (const float*)d_in[7];
  const float* gca = (const float*)d_in[8];
  float* out = (float*)d_out;

  char* wsp = (char*)d_ws;
  size_t off = 0;
  auto alloc = [&](size_t bytes) -> void* {
    void* p = (void*)(wsp + off);
    off = (off + bytes + 255) & ~(size_t)255;
    return p;
  };
  const size_t EB = (size_t)NB * CH * NPIX;
  u16*   Xb    = (u16*)alloc(EB * 2);
  u16*   Xt    = (u16*)alloc(EB * 2);
  u16*   Wb    = (u16*)alloc((size_t)MR * CH * 2);
  float* biasS = (float*)alloc((size_t)MR * 4);
  u16*   Vb    = (u16*)alloc(EB * 2);
  u16*   Qt    = (u16*)alloc((size_t)NB * NPIX * CQ * 2);
  u16*   Kt    = (u16*)alloc((size_t)NB * NPIX * CQ * 2);
  float* CAEp  = (float*)alloc((size_t)NB * 4 * CH * CH * 4);   // split-K partials
  u16*   Aca   = (u16*)alloc((size_t)NB * CH * CH * 2);

  k_prep_w<<<(MR * CH + 255) / 256, 256, 0, stream>>>(wq, bq, wk, bk, wv, bv, Wb, biasS);
  k_convert<<<dim3(64, 8, NB), 256, 0, stream>>>(x, Xb, Xt);

  // QKV: [640][512] x [4096][512]^T  -> Vb, Qt, Kt (+bias)
  gemm_nt<EP_QKV><<<dim3(MR / 128, NPIX / 128, NB), 256, 0, stream>>>(
      Wb, Xt, 0L, (long)NPIX * CH, CH, CH, 0, Vb, Qt, Kt, biasS);

  // CA energy split-K: Xb x Xb^T, K=1024 per slice -> CAEp[b*4+ks]
  gemm_nt<EP_PART><<<dim3(CH / 128, CH / 128, NB * 4), 256, 0, stream>>>(
      Xb, Xb, (long)CH * NPIX, (long)CH * NPIX, 1024, NPIX, 0,
      CAEp, nullptr, nullptr, nullptr);
  k_ca_softmax<<<NB * CH / 4, 256, 0, stream>>>(CAEp, Aca, gca);

  // fused position attention + CA epilogue -> out = gpa*PA + gca*CA + 2x
  k_pa_fused<<<NB * (NPIX / 64) * 2, 256, 0, stream>>>(
      Qt, Kt, Vb, Aca, Xt, x, out, gpa);
}